// Round 5
// baseline (1415.901 us; speedup 1.0000x reference)
//
#include <hip/hip_runtime.h>
#include <stdint.h>

// GemNet OutputBlock fused kernels for MI355X (gfx950).
// E = MLP(segment_sum(m .* (rbf@We_rbf))) @ We_out
// F = (ResMLP(ssilu(m@Wf_in)) .* (rbf@Wf_rbf)) @ Wf_out
//
// R5 change vs R4 (single isolated change):
//  - force_kernel __launch_bounds__(256,2) -> __launch_bounds__(256).
//    The min-waves hint made the compiler cap arch-VGPRs at 128 (same as R1)
//    and spill ~60 regs of the ~240-reg working set -> 581 MB scratch writes
//    (WRITE_SIZE evidence). Plain bound allocated 200 VGPR spill-free in R3;
//    budget at 2 waves/SIMD is 256 and demand ~240.

typedef __attribute__((ext_vector_type(8))) short bf16x8;
typedef __attribute__((ext_vector_type(4))) float f32x4;
typedef __attribute__((ext_vector_type(4))) unsigned u32x4;

#define INV_SQRT2 0.7071067811865476f

// ---- workspace layout (bytes) ----
#define XE_OFF     0ull
#define XE_BYTES   25600000ull                 // xE f32 [25000][256]
#define FWT_OFF    (XE_OFF + XE_BYTES)
#define FWT_BYTES  917504ull                   // 7 x [256][256] bf16, transposed+swizzled
#define EWT0_OFF   (FWT_OFF + FWT_BYTES)
#define EWT0_BYTES 65536ull                    // [128][256] bf16
#define EWTR_OFF   (EWT0_OFF + EWT0_BYTES)
#define EWTR_BYTES 196608ull                   // 6 x [128][128] bf16
#define W2F_OFF    (EWTR_OFF + EWTR_BYTES)
#define W2F_BYTES  16384ull                    // (Wf_rbf .* Wf_out)^T [256][32] bf16 (k padded)
#define W2E_OFF    (W2F_OFF + W2F_BYTES)
#define W2E_BYTES  16384ull                    // We_rbf^T [256][32] bf16 (k padded)

static __device__ __forceinline__ unsigned short f2bf(float f) {
  union { float f; unsigned u; } v; v.f = f;
  return (unsigned short)((v.u + 0x7fffu + ((v.u >> 16) & 1u)) >> 16);
}
static __device__ __forceinline__ float bf2f(unsigned short h) {
  union { unsigned u; float f; } v; v.u = ((unsigned)h) << 16;
  return v.f;
}
static __device__ __forceinline__ float ssilu(float x) {
  // silu(x)/0.6 = x * sigmoid(x) * 5/3
  return 1.6666666666666667f * x * __builtin_amdgcn_rcpf(1.0f + __expf(-x));
}
static __device__ __forceinline__ void gl16(const void* g, void* l) {
  // async global->LDS, 16B per lane; LDS dest is wave-uniform base + lane*16
  __builtin_amdgcn_global_load_lds(
      (const __attribute__((address_space(1))) void*)(unsigned long long)(uintptr_t)g,
      (__attribute__((address_space(3))) void*)(unsigned)(uintptr_t)l, 16, 0, 0);
}

// =====================================================================
// prep: weights f32 -> bf16, transposed to [out][in], XOR-swizzled with
// 4-bit row key so LDS-linear staging yields conflict-free b128 reads.
// =====================================================================
__global__ void prep_kernel(const float* __restrict__ We_rbf,
                            const float* __restrict__ We_in,
                            const float* __restrict__ We_res,
                            const float* __restrict__ Wf_rbf,
                            const float* __restrict__ Wf_in,
                            const float* __restrict__ Wf_res,
                            const float* __restrict__ Wf_out,
                            char* __restrict__ ws) {
  int idx = blockIdx.x * 256 + threadIdx.x;
  if (idx < 458752) {  // FWt: 7 stages [k=256][c=256] -> [c][k]
    int s = idx >> 16, r = idx & 65535, k = r >> 8, c = r & 255;
    float v = (s == 0) ? Wf_in[k * 256 + c] : Wf_res[(s - 1) * 65536 + k * 256 + c];
    *(unsigned short*)(ws + FWT_OFF + (unsigned long long)s * 131072 +
                       c * 512 + ((k * 2) ^ ((c & 15) << 4))) = f2bf(v);
    return;
  }
  idx -= 458752;
  if (idx < 32768) {  // EWt0: [k=256][c=128] -> [c][k]
    int k = idx >> 7, c = idx & 127;
    *(unsigned short*)(ws + EWT0_OFF + c * 512 + ((k * 2) ^ ((c & 15) << 4))) = f2bf(We_in[k * 128 + c]);
    return;
  }
  idx -= 32768;
  if (idx < 98304) {  // EWtR: 6 stages [k=128][c=128] -> [c][k], rows 256B
    int s = idx >> 14, r = idx & 16383, k = r >> 7, c = r & 127;
    *(unsigned short*)(ws + EWTR_OFF + (unsigned long long)s * 32768 +
                       c * 256 + ((k * 2) ^ ((c & 15) << 4))) = f2bf(We_res[s * 16384 + k * 128 + c]);
    return;
  }
  idx -= 98304;
  if (idx < 8192) {  // W2F: (Wf_rbf[k][c]*Wf_out[c])^T, k padded 16->32
    int c = idx >> 5, k = idx & 31;
    float v = (k < 16) ? Wf_rbf[k * 256 + c] * Wf_out[c] : 0.f;
    *(unsigned short*)(ws + W2F_OFF + c * 64 + ((k * 2) ^ ((c & 3) << 4))) = f2bf(v);
    return;
  }
  idx -= 8192;
  if (idx < 8192) {  // W2E: We_rbf^T, k padded
    int c = idx >> 5, k = idx & 31;
    float v = (k < 16) ? We_rbf[k * 256 + c] : 0.f;
    *(unsigned short*)(ws + W2E_OFF + c * 64 + ((k * 2) ^ ((c & 3) << 4))) = f2bf(v);
  }
}

// =====================================================================
// scatter: xE[id_j[e]] += m[e] .* (rbf[e] @ We_rbf)   (f32 atomics)
// =====================================================================
__global__ __launch_bounds__(256) void scatter_kernel(
    const float* __restrict__ m, const float* __restrict__ rbf,
    const int* __restrict__ id_j, const char* __restrict__ W2E,
    float* __restrict__ xE, int nE) {
  __shared__ char rbfA[8192];   // [128][32] bf16, swizzled (row&3)<<4
  __shared__ char wb[16384];    // W2E staged
  __shared__ int sI[128];
  const int tid = threadIdx.x;
  const int lane = tid & 63, q = lane >> 4, r15 = lane & 15;
  const int wid = tid >> 6, wrow = wid * 32;
  const long long row0 = (long long)blockIdx.x * 128;
  const f32x4 zf = {0.f, 0.f, 0.f, 0.f};

#pragma unroll
  for (int i = 0; i < 8; ++i) {
    const int idx = tid * 8 + i;
    const int row = idx >> 4, d = idx & 15;
    long long rg = row0 + row; if (rg >= nE) rg = nE - 1;
    *(unsigned short*)(rbfA + row * 64 + ((d * 2) ^ ((row & 3) << 4))) = f2bf(rbf[rg * 16 + d]);
    *(unsigned short*)(rbfA + row * 64 + (((16 + d) * 2) ^ ((row & 3) << 4))) = 0;
  }
  if (tid < 128) {
    long long rg = row0 + tid;
    sI[tid] = (rg < nE) ? id_j[rg] : -1;
  }
#pragma unroll
  for (int i = 0; i < 4; ++i) gl16(W2E + i * 4096 + tid * 16, wb + i * 4096 + tid * 16);
  asm volatile("s_waitcnt vmcnt(0)" ::: "memory");
  __syncthreads();

  bf16x8 ar[2];
#pragma unroll
  for (int fr = 0; fr < 2; ++fr) {
    const int row = wrow + fr * 16 + r15;
    ar[fr] = *(const bf16x8*)(rbfA + row * 64 + ((q * 16) ^ ((row & 3) << 4)));
  }
#pragma unroll
  for (int fcg = 0; fcg < 16; ++fcg) {
    const int ci = fcg * 16 + r15;
    bf16x8 bw = *(const bf16x8*)(wb + ci * 64 + ((q * 16) ^ ((ci & 3) << 4)));
#pragma unroll
    for (int fr = 0; fr < 2; ++fr) {
      f32x4 rw = __builtin_amdgcn_mfma_f32_16x16x32_bf16(ar[fr], bw, zf, 0, 0, 0);
      const int col = fcg * 16 + r15;
#pragma unroll
      for (int j = 0; j < 4; ++j) {
        const int rowl = wrow + fr * 16 + q * 4 + j;
        const int aid = sI[rowl];
        if (aid >= 0) {
          const long long rg = row0 + rowl;
          float mv = m[rg * 256 + col];
          atomicAdd(&xE[(long long)aid * 256 + col], mv * rw[j]);
        }
      }
    }
  }
}

// =====================================================================
// force: swapped-operand fused 7-GEMM chain, 128 rows/block, 4 waves x 32.
// No xbuf; depth-3 counted-vmcnt weight pipeline; 1 raw barrier per chunk.
// Chunk = 32 cols (16KB). 57 chunks total (56 chain + 1 W2F).
// =====================================================================
__global__ __launch_bounds__(256) void force_kernel(
    const float* __restrict__ m, const float* __restrict__ rbf,
    const char* __restrict__ FWt, const char* __restrict__ W2F,
    float* __restrict__ Fout, int nE) {
  __shared__ char wbuf[4][16384];
  const int tid = threadIdx.x;
  const int lane = tid & 63, q = lane >> 4, r15 = lane & 15;
  const int wid = tid >> 6, wrow = wid * 32;
  const long long row0 = (long long)blockIdx.x * 128;
  const f32x4 zf = {0.f, 0.f, 0.f, 0.f};
  const bool qh = (q >> 1) != 0;
  const int sA = ((q & 1) << 5) | r15;  // src lane for b-words 0,1
  const int sB = sA + 16;               // src lane for b-words 2,3

  long long rg[2];
  rg[0] = row0 + wrow + r15; if (rg[0] >= nE) rg[0] = nE - 1;
  rg[1] = row0 + wrow + 16 + r15; if (rg[1] >= nE) rg[1] = nE - 1;

  // stage chunks 0..2 (oldest VMEM ops -> counted vmcnt works)
#pragma unroll
  for (int cc = 0; cc < 3; ++cc)
#pragma unroll
    for (int i = 0; i < 4; ++i)
      gl16(FWt + cc * 16384 + i * 4096 + tid * 16, wbuf[cc] + i * 4096 + tid * 16);

  bf16x8 bA[2][8], bB[2][8];
  unsigned xs[8][2][2][2];  // residual checkpoint, c-layout [t][rt][f][p]

  // B-frags (= rows of m) : bA[rt][ks][e] = m[row][ks*32+q*8+e]
#pragma unroll
  for (int rt = 0; rt < 2; ++rt)
#pragma unroll
    for (int ks = 0; ks < 8; ++ks) {
      const float* p = m + rg[rt] * 256 + ks * 32 + q * 8;
      float4 v0 = *(const float4*)p;
      float4 v1 = *(const float4*)(p + 4);
      bf16x8 t;
      t[0] = (short)f2bf(v0.x); t[1] = (short)f2bf(v0.y);
      t[2] = (short)f2bf(v0.z); t[3] = (short)f2bf(v0.w);
      t[4] = (short)f2bf(v1.x); t[5] = (short)f2bf(v1.y);
      t[6] = (short)f2bf(v1.z); t[7] = (short)f2bf(v1.w);
      bA[rt][ks] = t;
    }

  for (int s = 0; s < 7; ++s) {
    const bool isS0 = (s == 0);
    const bool isRes = (s >= 2) && !(s & 1);
#pragma unroll
    for (int t = 0; t < 8; ++t) {
      const int c = s * 8 + t;
      // chunk c's loads done (c+1,c+2 still in flight = 8 outstanding)
      asm volatile("s_waitcnt vmcnt(8)" ::: "memory");
      __builtin_amdgcn_s_barrier();
      {  // issue chunk c+3 (clamped re-stage of W2F at the tail keeps
         // outstanding count uniform so vmcnt(8) is always correct)
        int cs = c + 3; if (cs > 56) cs = 56;
        const char* src = (cs < 56) ? (FWt + (unsigned long long)cs * 16384) : W2F;
        char* dst = (char*)wbuf + ((t + 3) & 3) * 16384;  // (c+3)&3 == (t+3)&3
#pragma unroll
        for (int i = 0; i < 4; ++i)
          gl16(src + i * 4096 + tid * 16, dst + i * 4096 + tid * 16);
      }
      const char* wb = (const char*)wbuf + (t & 3) * 16384;
      f32x4 acc[2][2] = {{zf, zf}, {zf, zf}};
#pragma unroll
      for (int ks = 0; ks < 8; ++ks) {
        const int kb = ks * 64 + q * 16;
        bf16x8 w0 = *(const bf16x8*)(wb + r15 * 512 + (kb ^ (r15 << 4)));
        bf16x8 w1 = *(const bf16x8*)(wb + (16 + r15) * 512 + (kb ^ (r15 << 4)));
        acc[0][0] = __builtin_amdgcn_mfma_f32_16x16x32_bf16(w0, bA[0][ks], acc[0][0], 0, 0, 0);
        acc[1][0] = __builtin_amdgcn_mfma_f32_16x16x32_bf16(w0, bA[1][ks], acc[1][0], 0, 0, 0);
        acc[0][1] = __builtin_amdgcn_mfma_f32_16x16x32_bf16(w1, bA[0][ks], acc[0][1], 0, 0, 0);
        acc[1][1] = __builtin_amdgcn_mfma_f32_16x16x32_bf16(w1, bA[1][ks], acc[1][1], 0, 0, 0);
      }
      // epilogue: y at c = t*32 + f*16 + 4q + j, row = own row (r15)
      unsigned yw[2][2][2];
#pragma unroll
      for (int rt = 0; rt < 2; ++rt)
#pragma unroll
        for (int f = 0; f < 2; ++f) {
          float o0 = ssilu(acc[rt][f][0]), o1 = ssilu(acc[rt][f][1]);
          float o2 = ssilu(acc[rt][f][2]), o3 = ssilu(acc[rt][f][3]);
          if (isRes) {
            const unsigned p0 = xs[t][rt][f][0], p1 = xs[t][rt][f][1];
            o0 = (bf2f((unsigned short)(p0 & 0xffff)) + o0) * INV_SQRT2;
            o1 = (bf2f((unsigned short)(p0 >> 16)) + o1) * INV_SQRT2;
            o2 = (bf2f((unsigned short)(p1 & 0xffff)) + o2) * INV_SQRT2;
            o3 = (bf2f((unsigned short)(p1 >> 16)) + o3) * INV_SQRT2;
          }
          const unsigned h01 = (unsigned)f2bf(o0) | ((unsigned)f2bf(o1) << 16);
          const unsigned h23 = (unsigned)f2bf(o2) | ((unsigned)f2bf(o3) << 16);
          if (isS0 | isRes) { xs[t][rt][f][0] = h01; xs[t][rt][f][1] = h23; }
          yw[rt][f][0] = h01; yw[rt][f][1] = h23;
        }
      // rebuild next-stage B-frag slot t via 4-lane permutation:
      // b[rt][t] word w <- lane (2(q&1)+(w>>1))<<4|r15, its yw[rt][q>>1][w&1]
      if (s < 6) {
#pragma unroll
        for (int rt = 0; rt < 2; ++rt) {
          unsigned vA0 = __shfl(yw[rt][0][0], sA, 64);
          unsigned vB0 = __shfl(yw[rt][1][0], sA, 64);
          unsigned W0 = qh ? vB0 : vA0;
          unsigned vA1 = __shfl(yw[rt][0][1], sA, 64);
          unsigned vB1 = __shfl(yw[rt][1][1], sA, 64);
          unsigned W1 = qh ? vB1 : vA1;
          unsigned vA2 = __shfl(yw[rt][0][0], sB, 64);
          unsigned vB2 = __shfl(yw[rt][1][0], sB, 64);
          unsigned W2 = qh ? vB2 : vA2;
          unsigned vA3 = __shfl(yw[rt][0][1], sB, 64);
          unsigned vB3 = __shfl(yw[rt][1][1], sB, 64);
          unsigned W3 = qh ? vB3 : vA3;
          u32x4 pk = {W0, W1, W2, W3};
          bB[rt][t] = __builtin_bit_cast(bf16x8, pk);
        }
      }
    }
    if (s < 6) {
#pragma unroll
      for (int rt = 0; rt < 2; ++rt)
#pragma unroll
        for (int ks = 0; ks < 8; ++ks) bA[rt][ks] = bB[rt][ks];
    }
  }

  // ---- final: rbfw = rbf @ (Wf_rbf .* Wf_out);  F[row] = sum_c x6 .* rbfw ----
  bf16x8 rbfb[2];
#pragma unroll
  for (int rt = 0; rt < 2; ++rt) {
    bf16x8 t = {0, 0, 0, 0, 0, 0, 0, 0};
    if (q < 2) {
      const float* p = rbf + rg[rt] * 16 + q * 8;
      float4 v0 = *(const float4*)p;
      float4 v1 = *(const float4*)(p + 4);
      t[0] = (short)f2bf(v0.x); t[1] = (short)f2bf(v0.y);
      t[2] = (short)f2bf(v0.z); t[3] = (short)f2bf(v0.w);
      t[4] = (short)f2bf(v1.x); t[5] = (short)f2bf(v1.y);
      t[6] = (short)f2bf(v1.z); t[7] = (short)f2bf(v1.w);
    }
    rbfb[rt] = t;
  }
  // chunk 56 (W2F) done; tail re-stages (8 loads) may remain outstanding
  asm volatile("s_waitcnt vmcnt(8)" ::: "memory");
  __builtin_amdgcn_s_barrier();
  const char* wb2 = (const char*)wbuf;  // 56 & 3 == 0
  float psum[2] = {0.f, 0.f};
#pragma unroll
  for (int tt = 0; tt < 16; ++tt) {
    const int crow = tt * 16 + r15;
    bf16x8 w2 = *(const bf16x8*)(wb2 + crow * 64 + ((q * 16) ^ ((r15 & 3) << 4)));
#pragma unroll
    for (int rt = 0; rt < 2; ++rt) {
      f32x4 rw = __builtin_amdgcn_mfma_f32_16x16x32_bf16(w2, rbfb[rt], zf, 0, 0, 0);
      const unsigned p0 = xs[tt >> 1][rt][tt & 1][0];
      const unsigned p1 = xs[tt >> 1][rt][tt & 1][1];
      psum[rt] += bf2f((unsigned short)(p0 & 0xffff)) * rw[0]
                + bf2f((unsigned short)(p0 >> 16)) * rw[1]
                + bf2f((unsigned short)(p1 & 0xffff)) * rw[2]
                + bf2f((unsigned short)(p1 >> 16)) * rw[3];
    }
  }
#pragma unroll
  for (int rt = 0; rt < 2; ++rt) {
    psum[rt] += __shfl_xor(psum[rt], 16, 64);
    psum[rt] += __shfl_xor(psum[rt], 32, 64);
  }
  if (q == 0) {
#pragma unroll
    for (int rt = 0; rt < 2; ++rt) {
      const long long r = row0 + wrow + rt * 16 + r15;
      if (r < nE) Fout[r] = psum[rt];
    }
  }
}

// =====================================================================
// energy MLP: xE[25000][256] -> ssilu(@We_in[256x128]) -> 3 residual(128) -> @We_out
// (small: 196 blocks; unchanged)
// =====================================================================
__global__ __launch_bounds__(256) void energy_kernel(
    const float* __restrict__ xE, const char* __restrict__ EWt0,
    const char* __restrict__ EWtR, const float* __restrict__ We_out,
    float* __restrict__ Eout, int nA) {
  __shared__ char xbuf[32768];  // [128][256B], swz key (row&15)<<4
  __shared__ char wbuf[16384];
  const int tid = threadIdx.x;
  const int lane = tid & 63, q = lane >> 4, r15 = lane & 15;
  const int wid = tid >> 6, wrow = wid * 32;
  const long long row0 = (long long)blockIdx.x * 128;
  const f32x4 zf = {0.f, 0.f, 0.f, 0.f};

  bf16x8 a[2][8];
  unsigned xs[4][2][2][2];

#pragma unroll
  for (int fr = 0; fr < 2; ++fr) {
#pragma unroll
    for (int ks = 0; ks < 8; ++ks) {
      long long rg = row0 + wrow + fr * 16 + r15;
      bf16x8 t = {0, 0, 0, 0, 0, 0, 0, 0};
      if (rg < nA) {
        const float* p = xE + rg * 256 + ks * 32 + q * 8;
        float4 v0 = *(const float4*)p;
        float4 v1 = *(const float4*)(p + 4);
        t[0] = (short)f2bf(v0.x); t[1] = (short)f2bf(v0.y);
        t[2] = (short)f2bf(v0.z); t[3] = (short)f2bf(v0.w);
        t[4] = (short)f2bf(v1.x); t[5] = (short)f2bf(v1.y);
        t[6] = (short)f2bf(v1.z); t[7] = (short)f2bf(v1.w);
      }
      a[fr][ks] = t;
    }
  }

  for (int s = 0; s < 7; ++s) {
    const int K2 = (s == 0) ? 512 : 256;  // bytes per weight row
    const int wchunk = 32 * K2;
    const int nld = wchunk >> 12;         // 4 or 2 16B-loads per thread
    const char* wsrc = (s == 0) ? EWt0 : (EWtR + (unsigned long long)(s - 1) * 32768);
    const int isS0 = (s == 0);
    const int isRes = (s >= 2) && ((s & 1) == 0);
#pragma unroll
    for (int c = 0; c < 4; ++c) {
      for (int i = 0; i < nld; ++i)
        gl16(wsrc + c * wchunk + i * 4096 + tid * 16, wbuf + i * 4096 + tid * 16);
      asm volatile("s_waitcnt vmcnt(0)" ::: "memory");
      __syncthreads();

      f32x4 acc[2][2] = {{zf, zf}, {zf, zf}};
      if (s == 0) {
#pragma unroll
        for (int ks = 0; ks < 8; ++ks) {
          const int kb = ks * 64 + q * 16;
          const int ci0 = r15, ci1 = 16 + r15;
          bf16x8 b0 = *(const bf16x8*)(wbuf + ci0 * 512 + (kb ^ ((ci0 & 15) << 4)));
          bf16x8 b1 = *(const bf16x8*)(wbuf + ci1 * 512 + (kb ^ ((ci1 & 15) << 4)));
          acc[0][0] = __builtin_amdgcn_mfma_f32_16x16x32_bf16(a[0][ks], b0, acc[0][0], 0, 0, 0);
          acc[1][0] = __builtin_amdgcn_mfma_f32_16x16x32_bf16(a[1][ks], b0, acc[1][0], 0, 0, 0);
          acc[0][1] = __builtin_amdgcn_mfma_f32_16x16x32_bf16(a[0][ks], b1, acc[0][1], 0, 0, 0);
          acc[1][1] = __builtin_amdgcn_mfma_f32_16x16x32_bf16(a[1][ks], b1, acc[1][1], 0, 0, 0);
        }
      } else {
#pragma unroll
        for (int ks = 0; ks < 4; ++ks) {
          const int kb = ks * 64 + q * 16;
          const int ci0 = r15, ci1 = 16 + r15;
          bf16x8 b0 = *(const bf16x8*)(wbuf + ci0 * 256 + (kb ^ ((ci0 & 15) << 4)));
          bf16x8 b1 = *(const bf16x8*)(wbuf + ci1 * 256 + (kb ^ ((ci1 & 15) << 4)));
          acc[0][0] = __builtin_amdgcn_mfma_f32_16x16x32_bf16(a[0][ks], b0, acc[0][0], 0, 0, 0);
          acc[1][0] = __builtin_amdgcn_mfma_f32_16x16x32_bf16(a[1][ks], b0, acc[1][0], 0, 0, 0);
          acc[0][1] = __builtin_amdgcn_mfma_f32_16x16x32_bf16(a[0][ks], b1, acc[0][1], 0, 0, 0);
          acc[1][1] = __builtin_amdgcn_mfma_f32_16x16x32_bf16(a[1][ks], b1, acc[1][1], 0, 0, 0);
        }
      }
#pragma unroll
      for (int fr = 0; fr < 2; ++fr) {
#pragma unroll
        for (int fc = 0; fc < 2; ++fc) {
          float o0 = ssilu(acc[fr][fc][0]), o1 = ssilu(acc[fr][fc][1]);
          float o2 = ssilu(acc[fr][fc][2]), o3 = ssilu(acc[fr][fc][3]);
          if (isRes) {
            const unsigned p0 = xs[c][fr][fc][0], p1 = xs[c][fr][fc][1];
            o0 = (bf2f((unsigned short)(p0 & 0xffff)) + o0) * INV_SQRT2;
            o1 = (bf2f((unsigned short)(p0 >> 16)) + o1) * INV_SQRT2;
            o2 = (bf2f((unsigned short)(p1 & 0xffff)) + o2) * INV_SQRT2;
            o3 = (bf2f((unsigned short)(p1 >> 16)) + o3) * INV_SQRT2;
          }
          const unsigned short h0 = f2bf(o0), h1 = f2bf(o1), h2 = f2bf(o2), h3 = f2bf(o3);
          if (isS0 | isRes) {
            xs[c][fr][fc][0] = (unsigned)h0 | ((unsigned)h1 << 16);
            xs[c][fr][fc][1] = (unsigned)h2 | ((unsigned)h3 << 16);
          }
          if (s < 6) {
            const int colb = (c * 32 + fc * 16 + r15) * 2;
            const int rb = wrow + fr * 16 + q * 4;
            *(unsigned short*)(xbuf + (rb + 0) * 256 + (colb ^ (((rb + 0) & 15) << 4))) = h0;
            *(unsigned short*)(xbuf + (rb + 1) * 256 + (colb ^ (((rb + 1) & 15) << 4))) = h1;
            *(unsigned short*)(xbuf + (rb + 2) * 256 + (colb ^ (((rb + 2) & 15) << 4))) = h2;
            *(unsigned short*)(xbuf + (rb + 3) * 256 + (colb ^ (((rb + 3) & 15) << 4))) = h3;
          }
        }
      }
      __syncthreads();
    }
    if (s < 6) {
#pragma unroll
      for (int fr = 0; fr < 2; ++fr) {
#pragma unroll
        for (int ks = 0; ks < 4; ++ks) {
          const int row = wrow + fr * 16 + r15;
          const int kb = ks * 64 + q * 16;
          a[fr][ks] = *(const bf16x8*)(xbuf + row * 256 + (kb ^ (r15 << 4)));
        }
      }
      __syncthreads();
    }
  }

  // final: E[row] = sum_c x[row,c] * We_out[c]
  float psum[2][4] = {{0.f, 0.f, 0.f, 0.f}, {0.f, 0.f, 0.f, 0.f}};
#pragma unroll
  for (int c = 0; c < 4; ++c) {
#pragma unroll
    for (int f = 0; f < 2; ++f) {
      const int col = c * 32 + f * 16 + r15;
      const float wo = We_out[col];
#pragma unroll
      for (int fr = 0; fr < 2; ++fr) {
        const unsigned p0 = xs[c][fr][f][0], p1 = xs[c][fr][f][1];
        psum[fr][0] += bf2f((unsigned short)(p0 & 0xffff)) * wo;
        psum[fr][1] += bf2f((unsigned short)(p0 >> 16)) * wo;
        psum[fr][2] += bf2f((unsigned short)(p1 & 0xffff)) * wo;
        psum[fr][3] += bf2f((unsigned short)(p1 >> 16)) * wo;
      }
    }
  }
#pragma unroll
  for (int off = 1; off < 16; off <<= 1) {
#pragma unroll
    for (int fr = 0; fr < 2; ++fr) {
#pragma unroll
      for (int j = 0; j < 4; ++j) psum[fr][j] += __shfl_xor(psum[fr][j], off, 64);
    }
  }
  if (r15 == 0) {
#pragma unroll
    for (int fr = 0; fr < 2; ++fr) {
#pragma unroll
      for (int j = 0; j < 4; ++j) {
        const long long rg = row0 + wrow + fr * 16 + q * 4 + j;
        if (rg < nA) Eout[rg] = psum[fr][j];
      }
    }
  }
}

// =====================================================================
extern "C" void kernel_launch(void* const* d_in, const int* in_sizes, int n_in,
                              void* d_out, int out_size, void* d_ws, size_t ws_size,
                              hipStream_t stream) {
  const float* m      = (const float*)d_in[1];
  const float* rbf    = (const float*)d_in[2];
  const int*   id_j   = (const int*)d_in[3];
  const float* We_rbf = (const float*)d_in[4];
  const float* We_in  = (const float*)d_in[5];
  const float* We_res = (const float*)d_in[6];
  const float* We_out = (const float*)d_in[7];
  const float* Wf_rbf = (const float*)d_in[8];
  const float* Wf_in  = (const float*)d_in[9];
  const float* Wf_res = (const float*)d_in[10];
  const float* Wf_out = (const float*)d_in[11];
  const int nA = in_sizes[0] / 128;   // 25000
  const int nE = in_sizes[1] / 256;   // 400000

  char* ws = (char*)d_ws;
  float* xE = (float*)(ws + XE_OFF);
  float* Eout = (float*)d_out;
  float* Fout = Eout + nA;

  prep_kernel<<<2368, 256, 0, stream>>>(We_rbf, We_in, We_res, Wf_rbf, Wf_in, Wf_res, Wf_out, ws);
  hipMemsetAsync(xE, 0, (size_t)nA * 256 * 4, stream);
  scatter_kernel<<<(nE + 127) / 128, 256, 0, stream>>>(m, rbf, id_j, ws + W2E_OFF, xE, nE);
  energy_kernel<<<(nA + 127) / 128, 256, 0, stream>>>(xE, ws + EWT0_OFF, ws + EWTR_OFF, We_out, Eout, nA);
  force_kernel<<<(nE + 127) / 128, 256, 0, stream>>>(m, rbf, ws + FWT_OFF, ws + W2F_OFF, Fout, nE);
}

// Round 6
// 1231.966 us; speedup vs baseline: 1.1493x; 1.1493x over previous
//
#include <hip/hip_runtime.h>
#include <stdint.h>

// GemNet OutputBlock fused kernels for MI355X (gfx950).
// E = MLP(segment_sum(m .* (rbf@We_rbf))) @ We_out
// F = (ResMLP(ssilu(m@Wf_in)) .* (rbf@Wf_rbf)) @ Wf_out
//
// R6 change vs R5 (force_kernel):
//  - 512-thread blocks (8 waves, 256 rows/block). A 512-thr block can only
//    launch if 8 waves fit per CU -> compiler is FORCED to total<=256 unified
//    regs/wave (the R5 failure: unconstrained alloc went >256 -> 1 wave/SIMD,
//    occupancy 11%). Demand ~236 fits -> no spills (unlike (256,2)'s arch-128
//    cap, R1/R4 evidence: 581MB scratch).
//  - Blocks 3125->1563: half the L2 staging traffic and per-CU barriers.
//  - Staging 2 gl16/wave/chunk -> depth-3 counted vmcnt(4).

typedef __attribute__((ext_vector_type(8))) short bf16x8;
typedef __attribute__((ext_vector_type(4))) float f32x4;
typedef __attribute__((ext_vector_type(4))) unsigned u32x4;

#define INV_SQRT2 0.7071067811865476f

// ---- workspace layout (bytes) ----
#define XE_OFF     0ull
#define XE_BYTES   25600000ull                 // xE f32 [25000][256]
#define FWT_OFF    (XE_OFF + XE_BYTES)
#define FWT_BYTES  917504ull                   // 7 x [256][256] bf16, transposed+swizzled
#define EWT0_OFF   (FWT_OFF + FWT_BYTES)
#define EWT0_BYTES 65536ull                    // [128][256] bf16
#define EWTR_OFF   (EWT0_OFF + EWT0_BYTES)
#define EWTR_BYTES 196608ull                   // 6 x [128][128] bf16
#define W2F_OFF    (EWTR_OFF + EWTR_BYTES)
#define W2F_BYTES  16384ull                    // (Wf_rbf .* Wf_out)^T [256][32] bf16 (k padded)
#define W2E_OFF    (W2F_OFF + W2F_BYTES)
#define W2E_BYTES  16384ull                    // We_rbf^T [256][32] bf16 (k padded)

static __device__ __forceinline__ unsigned short f2bf(float f) {
  union { float f; unsigned u; } v; v.f = f;
  return (unsigned short)((v.u + 0x7fffu + ((v.u >> 16) & 1u)) >> 16);
}
static __device__ __forceinline__ float bf2f(unsigned short h) {
  union { unsigned u; float f; } v; v.u = ((unsigned)h) << 16;
  return v.f;
}
static __device__ __forceinline__ float ssilu(float x) {
  // silu(x)/0.6 = x * sigmoid(x) * 5/3
  return 1.6666666666666667f * x * __builtin_amdgcn_rcpf(1.0f + __expf(-x));
}
static __device__ __forceinline__ void gl16(const void* g, void* l) {
  // async global->LDS, 16B per lane; LDS dest is wave-uniform base + lane*16
  __builtin_amdgcn_global_load_lds(
      (const __attribute__((address_space(1))) void*)(unsigned long long)(uintptr_t)g,
      (__attribute__((address_space(3))) void*)(unsigned)(uintptr_t)l, 16, 0, 0);
}

// =====================================================================
// prep: weights f32 -> bf16, transposed to [out][in], XOR-swizzled with
// 4-bit row key so LDS-linear staging yields conflict-free b128 reads.
// =====================================================================
__global__ void prep_kernel(const float* __restrict__ We_rbf,
                            const float* __restrict__ We_in,
                            const float* __restrict__ We_res,
                            const float* __restrict__ Wf_rbf,
                            const float* __restrict__ Wf_in,
                            const float* __restrict__ Wf_res,
                            const float* __restrict__ Wf_out,
                            char* __restrict__ ws) {
  int idx = blockIdx.x * 256 + threadIdx.x;
  if (idx < 458752) {  // FWt: 7 stages [k=256][c=256] -> [c][k]
    int s = idx >> 16, r = idx & 65535, k = r >> 8, c = r & 255;
    float v = (s == 0) ? Wf_in[k * 256 + c] : Wf_res[(s - 1) * 65536 + k * 256 + c];
    *(unsigned short*)(ws + FWT_OFF + (unsigned long long)s * 131072 +
                       c * 512 + ((k * 2) ^ ((c & 15) << 4))) = f2bf(v);
    return;
  }
  idx -= 458752;
  if (idx < 32768) {  // EWt0: [k=256][c=128] -> [c][k]
    int k = idx >> 7, c = idx & 127;
    *(unsigned short*)(ws + EWT0_OFF + c * 512 + ((k * 2) ^ ((c & 15) << 4))) = f2bf(We_in[k * 128 + c]);
    return;
  }
  idx -= 32768;
  if (idx < 98304) {  // EWtR: 6 stages [k=128][c=128] -> [c][k], rows 256B
    int s = idx >> 14, r = idx & 16383, k = r >> 7, c = r & 127;
    *(unsigned short*)(ws + EWTR_OFF + (unsigned long long)s * 32768 +
                       c * 256 + ((k * 2) ^ ((c & 15) << 4))) = f2bf(We_res[s * 16384 + k * 128 + c]);
    return;
  }
  idx -= 98304;
  if (idx < 8192) {  // W2F: (Wf_rbf[k][c]*Wf_out[c])^T, k padded 16->32
    int c = idx >> 5, k = idx & 31;
    float v = (k < 16) ? Wf_rbf[k * 256 + c] * Wf_out[c] : 0.f;
    *(unsigned short*)(ws + W2F_OFF + c * 64 + ((k * 2) ^ ((c & 3) << 4))) = f2bf(v);
    return;
  }
  idx -= 8192;
  if (idx < 8192) {  // W2E: We_rbf^T, k padded
    int c = idx >> 5, k = idx & 31;
    float v = (k < 16) ? We_rbf[k * 256 + c] : 0.f;
    *(unsigned short*)(ws + W2E_OFF + c * 64 + ((k * 2) ^ ((c & 3) << 4))) = f2bf(v);
  }
}

// =====================================================================
// scatter: xE[id_j[e]] += m[e] .* (rbf[e] @ We_rbf)   (f32 atomics)
// =====================================================================
__global__ __launch_bounds__(256) void scatter_kernel(
    const float* __restrict__ m, const float* __restrict__ rbf,
    const int* __restrict__ id_j, const char* __restrict__ W2E,
    float* __restrict__ xE, int nE) {
  __shared__ char rbfA[8192];   // [128][32] bf16, swizzled (row&3)<<4
  __shared__ char wb[16384];    // W2E staged
  __shared__ int sI[128];
  const int tid = threadIdx.x;
  const int lane = tid & 63, q = lane >> 4, r15 = lane & 15;
  const int wid = tid >> 6, wrow = wid * 32;
  const long long row0 = (long long)blockIdx.x * 128;
  const f32x4 zf = {0.f, 0.f, 0.f, 0.f};

#pragma unroll
  for (int i = 0; i < 8; ++i) {
    const int idx = tid * 8 + i;
    const int row = idx >> 4, d = idx & 15;
    long long rg = row0 + row; if (rg >= nE) rg = nE - 1;
    *(unsigned short*)(rbfA + row * 64 + ((d * 2) ^ ((row & 3) << 4))) = f2bf(rbf[rg * 16 + d]);
    *(unsigned short*)(rbfA + row * 64 + (((16 + d) * 2) ^ ((row & 3) << 4))) = 0;
  }
  if (tid < 128) {
    long long rg = row0 + tid;
    sI[tid] = (rg < nE) ? id_j[rg] : -1;
  }
#pragma unroll
  for (int i = 0; i < 4; ++i) gl16(W2E + i * 4096 + tid * 16, wb + i * 4096 + tid * 16);
  asm volatile("s_waitcnt vmcnt(0)" ::: "memory");
  __syncthreads();

  bf16x8 ar[2];
#pragma unroll
  for (int fr = 0; fr < 2; ++fr) {
    const int row = wrow + fr * 16 + r15;
    ar[fr] = *(const bf16x8*)(rbfA + row * 64 + ((q * 16) ^ ((row & 3) << 4)));
  }
#pragma unroll
  for (int fcg = 0; fcg < 16; ++fcg) {
    const int ci = fcg * 16 + r15;
    bf16x8 bw = *(const bf16x8*)(wb + ci * 64 + ((q * 16) ^ ((ci & 3) << 4)));
#pragma unroll
    for (int fr = 0; fr < 2; ++fr) {
      f32x4 rw = __builtin_amdgcn_mfma_f32_16x16x32_bf16(ar[fr], bw, zf, 0, 0, 0);
      const int col = fcg * 16 + r15;
#pragma unroll
      for (int j = 0; j < 4; ++j) {
        const int rowl = wrow + fr * 16 + q * 4 + j;
        const int aid = sI[rowl];
        if (aid >= 0) {
          const long long rg = row0 + rowl;
          float mv = m[rg * 256 + col];
          atomicAdd(&xE[(long long)aid * 256 + col], mv * rw[j]);
        }
      }
    }
  }
}

// =====================================================================
// force: swapped-operand fused 7-GEMM chain, 256 rows/block, 8 waves x 32.
// No xbuf; depth-3 counted-vmcnt weight pipeline; 1 raw barrier per chunk.
// Chunk = 32 cols (16KB). 57 chunks total (56 chain + 1 W2F).
// 512-thread block forces total regs <= 256/wave (8 waves must co-reside).
// =====================================================================
__global__ __launch_bounds__(512) void force_kernel(
    const float* __restrict__ m, const float* __restrict__ rbf,
    const char* __restrict__ FWt, const char* __restrict__ W2F,
    float* __restrict__ Fout, int nE) {
  __shared__ char wbuf[4][16384];
  const int tid = threadIdx.x;
  const int lane = tid & 63, q = lane >> 4, r15 = lane & 15;
  const int wid = tid >> 6, wrow = wid * 32;   // wid 0..7 -> 256 rows/block
  const long long row0 = (long long)blockIdx.x * 256;
  const f32x4 zf = {0.f, 0.f, 0.f, 0.f};
  const bool qh = (q >> 1) != 0;
  const int sA = ((q & 1) << 5) | r15;  // src lane for b-words 0,1
  const int sB = sA + 16;               // src lane for b-words 2,3

  long long rg[2];
  rg[0] = row0 + wrow + r15; if (rg[0] >= nE) rg[0] = nE - 1;
  rg[1] = row0 + wrow + 16 + r15; if (rg[1] >= nE) rg[1] = nE - 1;

  // stage chunks 0..2 (oldest VMEM ops -> counted vmcnt works)
#pragma unroll
  for (int cc = 0; cc < 3; ++cc)
#pragma unroll
    for (int i = 0; i < 2; ++i)
      gl16(FWt + cc * 16384 + i * 8192 + tid * 16, wbuf[cc] + i * 8192 + tid * 16);

  bf16x8 bA[2][8], bB[2][8];
  unsigned xs[8][2][2][2];  // residual checkpoint, c-layout [t][rt][f][p]

  // B-frags (= rows of m) : bA[rt][ks][e] = m[row][ks*32+q*8+e]
#pragma unroll
  for (int rt = 0; rt < 2; ++rt)
#pragma unroll
    for (int ks = 0; ks < 8; ++ks) {
      const float* p = m + rg[rt] * 256 + ks * 32 + q * 8;
      float4 v0 = *(const float4*)p;
      float4 v1 = *(const float4*)(p + 4);
      bf16x8 t;
      t[0] = (short)f2bf(v0.x); t[1] = (short)f2bf(v0.y);
      t[2] = (short)f2bf(v0.z); t[3] = (short)f2bf(v0.w);
      t[4] = (short)f2bf(v1.x); t[5] = (short)f2bf(v1.y);
      t[6] = (short)f2bf(v1.z); t[7] = (short)f2bf(v1.w);
      bA[rt][ks] = t;
    }

  for (int s = 0; s < 7; ++s) {
    const bool isS0 = (s == 0);
    const bool isRes = (s >= 2) && !(s & 1);
#pragma unroll
    for (int t = 0; t < 8; ++t) {
      const int c = s * 8 + t;
      // chunk c's 2 loads done (c+1,c+2 in flight = 4 outstanding)
      asm volatile("s_waitcnt vmcnt(4)" ::: "memory");
      __builtin_amdgcn_s_barrier();
      {  // issue chunk c+3 (clamped re-stage of W2F at the tail keeps
         // outstanding count uniform so vmcnt(4) is always correct)
        int cs = c + 3; if (cs > 56) cs = 56;
        const char* src = (cs < 56) ? (FWt + (unsigned long long)cs * 16384) : W2F;
        char* dst = (char*)wbuf + ((t + 3) & 3) * 16384;  // (c+3)&3 == (t+3)&3
#pragma unroll
        for (int i = 0; i < 2; ++i)
          gl16(src + i * 8192 + tid * 16, dst + i * 8192 + tid * 16);
      }
      const char* wb = (const char*)wbuf + (t & 3) * 16384;
      f32x4 acc[2][2] = {{zf, zf}, {zf, zf}};
#pragma unroll
      for (int ks = 0; ks < 8; ++ks) {
        const int kb = ks * 64 + q * 16;
        bf16x8 w0 = *(const bf16x8*)(wb + r15 * 512 + (kb ^ (r15 << 4)));
        bf16x8 w1 = *(const bf16x8*)(wb + (16 + r15) * 512 + (kb ^ (r15 << 4)));
        acc[0][0] = __builtin_amdgcn_mfma_f32_16x16x32_bf16(w0, bA[0][ks], acc[0][0], 0, 0, 0);
        acc[1][0] = __builtin_amdgcn_mfma_f32_16x16x32_bf16(w0, bA[1][ks], acc[1][0], 0, 0, 0);
        acc[0][1] = __builtin_amdgcn_mfma_f32_16x16x32_bf16(w1, bA[0][ks], acc[0][1], 0, 0, 0);
        acc[1][1] = __builtin_amdgcn_mfma_f32_16x16x32_bf16(w1, bA[1][ks], acc[1][1], 0, 0, 0);
      }
      // epilogue: y at col c = t*32 + f*16 + 4q + j, row = own row (r15)
      unsigned yw[2][2][2];
#pragma unroll
      for (int rt = 0; rt < 2; ++rt)
#pragma unroll
        for (int f = 0; f < 2; ++f) {
          float o0 = ssilu(acc[rt][f][0]), o1 = ssilu(acc[rt][f][1]);
          float o2 = ssilu(acc[rt][f][2]), o3 = ssilu(acc[rt][f][3]);
          if (isRes) {
            const unsigned p0 = xs[t][rt][f][0], p1 = xs[t][rt][f][1];
            o0 = (bf2f((unsigned short)(p0 & 0xffff)) + o0) * INV_SQRT2;
            o1 = (bf2f((unsigned short)(p0 >> 16)) + o1) * INV_SQRT2;
            o2 = (bf2f((unsigned short)(p1 & 0xffff)) + o2) * INV_SQRT2;
            o3 = (bf2f((unsigned short)(p1 >> 16)) + o3) * INV_SQRT2;
          }
          const unsigned h01 = (unsigned)f2bf(o0) | ((unsigned)f2bf(o1) << 16);
          const unsigned h23 = (unsigned)f2bf(o2) | ((unsigned)f2bf(o3) << 16);
          if (isS0 | isRes) { xs[t][rt][f][0] = h01; xs[t][rt][f][1] = h23; }
          yw[rt][f][0] = h01; yw[rt][f][1] = h23;
        }
      // rebuild next-stage B-frag slot t via 4-lane permutation:
      // b[rt][t] word w <- lane (2(q&1)+(w>>1))<<4|r15, its yw[rt][q>>1][w&1]
      if (s < 6) {
#pragma unroll
        for (int rt = 0; rt < 2; ++rt) {
          unsigned vA0 = __shfl(yw[rt][0][0], sA, 64);
          unsigned vB0 = __shfl(yw[rt][1][0], sA, 64);
          unsigned W0 = qh ? vB0 : vA0;
          unsigned vA1 = __shfl(yw[rt][0][1], sA, 64);
          unsigned vB1 = __shfl(yw[rt][1][1], sA, 64);
          unsigned W1 = qh ? vB1 : vA1;
          unsigned vA2 = __shfl(yw[rt][0][0], sB, 64);
          unsigned vB2 = __shfl(yw[rt][1][0], sB, 64);
          unsigned W2 = qh ? vB2 : vA2;
          unsigned vA3 = __shfl(yw[rt][0][1], sB, 64);
          unsigned vB3 = __shfl(yw[rt][1][1], sB, 64);
          unsigned W3 = qh ? vB3 : vA3;
          u32x4 pk = {W0, W1, W2, W3};
          bB[rt][t] = __builtin_bit_cast(bf16x8, pk);
        }
      }
    }
    if (s < 6) {
#pragma unroll
      for (int rt = 0; rt < 2; ++rt)
#pragma unroll
        for (int ks = 0; ks < 8; ++ks) bA[rt][ks] = bB[rt][ks];
    }
  }

  // ---- final: rbfw = rbf @ (Wf_rbf .* Wf_out);  F[row] = sum_c x6 .* rbfw ----
  bf16x8 rbfb[2];
#pragma unroll
  for (int rt = 0; rt < 2; ++rt) {
    bf16x8 t = {0, 0, 0, 0, 0, 0, 0, 0};
    if (q < 2) {
      const float* p = rbf + rg[rt] * 16 + q * 8;
      float4 v0 = *(const float4*)p;
      float4 v1 = *(const float4*)(p + 4);
      t[0] = (short)f2bf(v0.x); t[1] = (short)f2bf(v0.y);
      t[2] = (short)f2bf(v0.z); t[3] = (short)f2bf(v0.w);
      t[4] = (short)f2bf(v1.x); t[5] = (short)f2bf(v1.y);
      t[6] = (short)f2bf(v1.z); t[7] = (short)f2bf(v1.w);
    }
    rbfb[rt] = t;
  }
  // chunk 56 (W2F, slot 0) staged at c=53; tail re-stages (c=54,55 -> 4 ops)
  // may remain outstanding
  asm volatile("s_waitcnt vmcnt(4)" ::: "memory");
  __builtin_amdgcn_s_barrier();
  const char* wb2 = (const char*)wbuf;  // 56 & 3 == 0
  float psum[2] = {0.f, 0.f};
#pragma unroll
  for (int tt = 0; tt < 16; ++tt) {
    const int crow = tt * 16 + r15;
    bf16x8 w2 = *(const bf16x8*)(wb2 + crow * 64 + ((q * 16) ^ ((r15 & 3) << 4)));
#pragma unroll
    for (int rt = 0; rt < 2; ++rt) {
      f32x4 rw = __builtin_amdgcn_mfma_f32_16x16x32_bf16(w2, rbfb[rt], zf, 0, 0, 0);
      const unsigned p0 = xs[tt >> 1][rt][tt & 1][0];
      const unsigned p1 = xs[tt >> 1][rt][tt & 1][1];
      psum[rt] += bf2f((unsigned short)(p0 & 0xffff)) * rw[0]
                + bf2f((unsigned short)(p0 >> 16)) * rw[1]
                + bf2f((unsigned short)(p1 & 0xffff)) * rw[2]
                + bf2f((unsigned short)(p1 >> 16)) * rw[3];
    }
  }
#pragma unroll
  for (int rt = 0; rt < 2; ++rt) {
    psum[rt] += __shfl_xor(psum[rt], 16, 64);
    psum[rt] += __shfl_xor(psum[rt], 32, 64);
  }
  if (q == 0) {
#pragma unroll
    for (int rt = 0; rt < 2; ++rt) {
      const long long r = row0 + wrow + rt * 16 + r15;
      if (r < nE) Fout[r] = psum[rt];
    }
  }
}

// =====================================================================
// energy MLP: xE[25000][256] -> ssilu(@We_in[256x128]) -> 3 residual(128) -> @We_out
// (small: 196 blocks; unchanged)
// =====================================================================
__global__ __launch_bounds__(256) void energy_kernel(
    const float* __restrict__ xE, const char* __restrict__ EWt0,
    const char* __restrict__ EWtR, const float* __restrict__ We_out,
    float* __restrict__ Eout, int nA) {
  __shared__ char xbuf[32768];  // [128][256B], swz key (row&15)<<4
  __shared__ char wbuf[16384];
  const int tid = threadIdx.x;
  const int lane = tid & 63, q = lane >> 4, r15 = lane & 15;
  const int wid = tid >> 6, wrow = wid * 32;
  const long long row0 = (long long)blockIdx.x * 128;
  const f32x4 zf = {0.f, 0.f, 0.f, 0.f};

  bf16x8 a[2][8];
  unsigned xs[4][2][2][2];

#pragma unroll
  for (int fr = 0; fr < 2; ++fr) {
#pragma unroll
    for (int ks = 0; ks < 8; ++ks) {
      long long rg = row0 + wrow + fr * 16 + r15;
      bf16x8 t = {0, 0, 0, 0, 0, 0, 0, 0};
      if (rg < nA) {
        const float* p = xE + rg * 256 + ks * 32 + q * 8;
        float4 v0 = *(const float4*)p;
        float4 v1 = *(const float4*)(p + 4);
        t[0] = (short)f2bf(v0.x); t[1] = (short)f2bf(v0.y);
        t[2] = (short)f2bf(v0.z); t[3] = (short)f2bf(v0.w);
        t[4] = (short)f2bf(v1.x); t[5] = (short)f2bf(v1.y);
        t[6] = (short)f2bf(v1.z); t[7] = (short)f2bf(v1.w);
      }
      a[fr][ks] = t;
    }
  }

  for (int s = 0; s < 7; ++s) {
    const int K2 = (s == 0) ? 512 : 256;  // bytes per weight row
    const int wchunk = 32 * K2;
    const int nld = wchunk >> 12;         // 4 or 2 16B-loads per thread
    const char* wsrc = (s == 0) ? EWt0 : (EWtR + (unsigned long long)(s - 1) * 32768);
    const int isS0 = (s == 0);
    const int isRes = (s >= 2) && ((s & 1) == 0);
#pragma unroll
    for (int c = 0; c < 4; ++c) {
      for (int i = 0; i < nld; ++i)
        gl16(wsrc + c * wchunk + i * 4096 + tid * 16, wbuf + i * 4096 + tid * 16);
      asm volatile("s_waitcnt vmcnt(0)" ::: "memory");
      __syncthreads();

      f32x4 acc[2][2] = {{zf, zf}, {zf, zf}};
      if (s == 0) {
#pragma unroll
        for (int ks = 0; ks < 8; ++ks) {
          const int kb = ks * 64 + q * 16;
          const int ci0 = r15, ci1 = 16 + r15;
          bf16x8 b0 = *(const bf16x8*)(wbuf + ci0 * 512 + (kb ^ ((ci0 & 15) << 4)));
          bf16x8 b1 = *(const bf16x8*)(wbuf + ci1 * 512 + (kb ^ ((ci1 & 15) << 4)));
          acc[0][0] = __builtin_amdgcn_mfma_f32_16x16x32_bf16(a[0][ks], b0, acc[0][0], 0, 0, 0);
          acc[1][0] = __builtin_amdgcn_mfma_f32_16x16x32_bf16(a[1][ks], b0, acc[1][0], 0, 0, 0);
          acc[0][1] = __builtin_amdgcn_mfma_f32_16x16x32_bf16(a[0][ks], b1, acc[0][1], 0, 0, 0);
          acc[1][1] = __builtin_amdgcn_mfma_f32_16x16x32_bf16(a[1][ks], b1, acc[1][1], 0, 0, 0);
        }
      } else {
#pragma unroll
        for (int ks = 0; ks < 4; ++ks) {
          const int kb = ks * 64 + q * 16;
          const int ci0 = r15, ci1 = 16 + r15;
          bf16x8 b0 = *(const bf16x8*)(wbuf + ci0 * 256 + (kb ^ ((ci0 & 15) << 4)));
          bf16x8 b1 = *(const bf16x8*)(wbuf + ci1 * 256 + (kb ^ ((ci1 & 15) << 4)));
          acc[0][0] = __builtin_amdgcn_mfma_f32_16x16x32_bf16(a[0][ks], b0, acc[0][0], 0, 0, 0);
          acc[1][0] = __builtin_amdgcn_mfma_f32_16x16x32_bf16(a[1][ks], b0, acc[1][0], 0, 0, 0);
          acc[0][1] = __builtin_amdgcn_mfma_f32_16x16x32_bf16(a[0][ks], b1, acc[0][1], 0, 0, 0);
          acc[1][1] = __builtin_amdgcn_mfma_f32_16x16x32_bf16(a[1][ks], b1, acc[1][1], 0, 0, 0);
        }
      }
#pragma unroll
      for (int fr = 0; fr < 2; ++fr) {
#pragma unroll
        for (int fc = 0; fc < 2; ++fc) {
          float o0 = ssilu(acc[fr][fc][0]), o1 = ssilu(acc[fr][fc][1]);
          float o2 = ssilu(acc[fr][fc][2]), o3 = ssilu(acc[fr][fc][3]);
          if (isRes) {
            const unsigned p0 = xs[c][fr][fc][0], p1 = xs[c][fr][fc][1];
            o0 = (bf2f((unsigned short)(p0 & 0xffff)) + o0) * INV_SQRT2;
            o1 = (bf2f((unsigned short)(p0 >> 16)) + o1) * INV_SQRT2;
            o2 = (bf2f((unsigned short)(p1 & 0xffff)) + o2) * INV_SQRT2;
            o3 = (bf2f((unsigned short)(p1 >> 16)) + o3) * INV_SQRT2;
          }
          const unsigned short h0 = f2bf(o0), h1 = f2bf(o1), h2 = f2bf(o2), h3 = f2bf(o3);
          if (isS0 | isRes) {
            xs[c][fr][fc][0] = (unsigned)h0 | ((unsigned)h1 << 16);
            xs[c][fr][fc][1] = (unsigned)h2 | ((unsigned)h3 << 16);
          }
          if (s < 6) {
            const int colb = (c * 32 + fc * 16 + r15) * 2;
            const int rb = wrow + fr * 16 + q * 4;
            *(unsigned short*)(xbuf + (rb + 0) * 256 + (colb ^ (((rb + 0) & 15) << 4))) = h0;
            *(unsigned short*)(xbuf + (rb + 1) * 256 + (colb ^ (((rb + 1) & 15) << 4))) = h1;
            *(unsigned short*)(xbuf + (rb + 2) * 256 + (colb ^ (((rb + 2) & 15) << 4))) = h2;
            *(unsigned short*)(xbuf + (rb + 3) * 256 + (colb ^ (((rb + 3) & 15) << 4))) = h3;
          }
        }
      }
      __syncthreads();
    }
    if (s < 6) {
#pragma unroll
      for (int fr = 0; fr < 2; ++fr) {
#pragma unroll
        for (int ks = 0; ks < 4; ++ks) {
          const int row = wrow + fr * 16 + r15;
          const int kb = ks * 64 + q * 16;
          a[fr][ks] = *(const bf16x8*)(xbuf + row * 256 + (kb ^ (r15 << 4)));
        }
      }
      __syncthreads();
    }
  }

  // final: E[row] = sum_c x[row,c] * We_out[c]
  float psum[2][4] = {{0.f, 0.f, 0.f, 0.f}, {0.f, 0.f, 0.f, 0.f}};
#pragma unroll
  for (int c = 0; c < 4; ++c) {
#pragma unroll
    for (int f = 0; f < 2; ++f) {
      const int col = c * 32 + f * 16 + r15;
      const float wo = We_out[col];
#pragma unroll
      for (int fr = 0; fr < 2; ++fr) {
        const unsigned p0 = xs[c][fr][f][0], p1 = xs[c][fr][f][1];
        psum[fr][0] += bf2f((unsigned short)(p0 & 0xffff)) * wo;
        psum[fr][1] += bf2f((unsigned short)(p0 >> 16)) * wo;
        psum[fr][2] += bf2f((unsigned short)(p1 & 0xffff)) * wo;
        psum[fr][3] += bf2f((unsigned short)(p1 >> 16)) * wo;
      }
    }
  }
#pragma unroll
  for (int off = 1; off < 16; off <<= 1) {
#pragma unroll
    for (int fr = 0; fr < 2; ++fr) {
#pragma unroll
      for (int j = 0; j < 4; ++j) psum[fr][j] += __shfl_xor(psum[fr][j], off, 64);
    }
  }
  if (r15 == 0) {
#pragma unroll
    for (int fr = 0; fr < 2; ++fr) {
#pragma unroll
      for (int j = 0; j < 4; ++j) {
        const long long rg = row0 + wrow + fr * 16 + q * 4 + j;
        if (rg < nA) Eout[rg] = psum[fr][j];
      }
    }
  }
}

// =====================================================================
extern "C" void kernel_launch(void* const* d_in, const int* in_sizes, int n_in,
                              void* d_out, int out_size, void* d_ws, size_t ws_size,
                              hipStream_t stream) {
  const float* m      = (const float*)d_in[1];
  const float* rbf    = (const float*)d_in[2];
  const int*   id_j   = (const int*)d_in[3];
  const float* We_rbf = (const float*)d_in[4];
  const float* We_in  = (const float*)d_in[5];
  const float* We_res = (const float*)d_in[6];
  const float* We_out = (const float*)d_in[7];
  const float* Wf_rbf = (const float*)d_in[8];
  const float* Wf_in  = (const float*)d_in[9];
  const float* Wf_res = (const float*)d_in[10];
  const float* Wf_out = (const float*)d_in[11];
  const int nA = in_sizes[0] / 128;   // 25000
  const int nE = in_sizes[1] / 256;   // 400000

  char* ws = (char*)d_ws;
  float* xE = (float*)(ws + XE_OFF);
  float* Eout = (float*)d_out;
  float* Fout = Eout + nA;

  prep_kernel<<<2368, 256, 0, stream>>>(We_rbf, We_in, We_res, Wf_rbf, Wf_in, Wf_res, Wf_out, ws);
  hipMemsetAsync(xE, 0, (size_t)nA * 256 * 4, stream);
  scatter_kernel<<<(nE + 127) / 128, 256, 0, stream>>>(m, rbf, id_j, ws + W2E_OFF, xE, nE);
  energy_kernel<<<(nA + 127) / 128, 256, 0, stream>>>(xE, ws + EWT0_OFF, ws + EWTR_OFF, We_out, Eout, nA);
  force_kernel<<<(nE + 255) / 256, 512, 0, stream>>>(m, rbf, ws + FWT_OFF, ws + W2F_OFF, Fout, nE);
}

// Round 7
// 1101.812 us; speedup vs baseline: 1.2851x; 1.1181x over previous
//
#include <hip/hip_runtime.h>
#include <stdint.h>

// GemNet OutputBlock fused kernels for MI355X (gfx950).
// E = MLP(segment_sum(m .* (rbf@We_rbf))) @ We_out
// F = (ResMLP(ssilu(m@Wf_in)) .* (rbf@Wf_rbf)) @ Wf_out
//
// R7 redesign (force_kernel): column-sliced.
//  - Wave wid owns output cols 32*wid..+31 for ALL 64 rows of the block;
//    its W-slice lives in 64 VGPRs, loaded coalesced from a per-wave-
//    contiguous weight layout (FWR) directly global->regs (L2-hot). No W
//    LDS staging, no counted vmcnt, no shuffle network (R6's 477MB spill
//    + LDS-pipe saturation both die: demand ~130 regs).
//  - X in 2x32KB LDS double buffer; y written once per element per stage
//    (ds_write_b64, lane-local rows); residual checkpoint xs = 16 regs.
//  - 8 barriers/block (was 56). 6250 blocks x 512 thr; 400000 = 6250*64.

typedef __attribute__((ext_vector_type(8))) short bf16x8;
typedef __attribute__((ext_vector_type(4))) float f32x4;
typedef __attribute__((ext_vector_type(2))) unsigned u32x2;

#define INV_SQRT2 0.7071067811865476f

// ---- workspace layout (bytes) ----
#define XE_OFF     0ull
#define XE_BYTES   25600000ull                 // xE f32 [25000][256]
#define FWT_OFF    (XE_OFF + XE_BYTES)
#define FWT_BYTES  917504ull                   // FWR: 7 x [8 slice][2 h][8 ks][64 lane]x16B
#define EWT0_OFF   (FWT_OFF + FWT_BYTES)
#define EWT0_BYTES 65536ull                    // [128][256] bf16
#define EWTR_OFF   (EWT0_OFF + EWT0_BYTES)
#define EWTR_BYTES 196608ull                   // 6 x [128][128] bf16
#define W2F_OFF    (EWTR_OFF + EWTR_BYTES)
#define W2F_BYTES  16384ull                    // W2FR: [8 slice][2 h][64 lane]x16B
#define W2E_OFF    (W2F_OFF + W2F_BYTES)
#define W2E_BYTES  16384ull                    // We_rbf^T [256][32] bf16 (k padded)

static __device__ __forceinline__ unsigned short f2bf(float f) {
  union { float f; unsigned u; } v; v.f = f;
  return (unsigned short)((v.u + 0x7fffu + ((v.u >> 16) & 1u)) >> 16);
}
static __device__ __forceinline__ float bf2f(unsigned short h) {
  union { unsigned u; float f; } v; v.u = ((unsigned)h) << 16;
  return v.f;
}
static __device__ __forceinline__ float ssilu(float x) {
  // silu(x)/0.6 = x * sigmoid(x) * 5/3
  return 1.6666666666666667f * x * __builtin_amdgcn_rcpf(1.0f + __expf(-x));
}
static __device__ __forceinline__ void gl16(const void* g, void* l) {
  __builtin_amdgcn_global_load_lds(
      (const __attribute__((address_space(1))) void*)(unsigned long long)(uintptr_t)g,
      (__attribute__((address_space(3))) void*)(unsigned)(uintptr_t)l, 16, 0, 0);
}

// =====================================================================
// prep: weights f32 -> bf16 into frag-ready layouts.
//  FWR  (force chain): [s][slice w][h][ks][lane]x16B; lane gives
//    c = 32w+16h+(lane&15), k = 32ks+8*(lane>>4)+e  -> W_s[k][c]
//  W2FR (force gating): [w][h][lane]x16B; k = 8*(lane>>4)+e (pad k>=16)
//  EWt0/EWtR (energy, LDS-staged path): [c][k] XOR-swizzled, unchanged.
//  W2E (scatter): unchanged.
// =====================================================================
__global__ void prep_kernel(const float* __restrict__ We_rbf,
                            const float* __restrict__ We_in,
                            const float* __restrict__ We_res,
                            const float* __restrict__ Wf_rbf,
                            const float* __restrict__ Wf_in,
                            const float* __restrict__ Wf_res,
                            const float* __restrict__ Wf_out,
                            char* __restrict__ ws) {
  int idx = blockIdx.x * 256 + threadIdx.x;
  if (idx < 458752) {  // FWR
    int s = idx >> 16, r = idx & 65535;
    int w = r >> 13, h = (r >> 12) & 1, ks = (r >> 9) & 7, lane = (r >> 3) & 63, e = r & 7;
    int c = w * 32 + h * 16 + (lane & 15);
    int k = ks * 32 + (lane >> 4) * 8 + e;
    float v = (s == 0) ? Wf_in[k * 256 + c] : Wf_res[(s - 1) * 65536 + k * 256 + c];
    *(unsigned short*)(ws + FWT_OFF + (unsigned long long)s * 131072 + (unsigned)r * 2) = f2bf(v);
    return;
  }
  idx -= 458752;
  if (idx < 32768) {  // EWt0: [k=256][c=128] -> [c][k]
    int k = idx >> 7, c = idx & 127;
    *(unsigned short*)(ws + EWT0_OFF + c * 512 + ((k * 2) ^ ((c & 15) << 4))) = f2bf(We_in[k * 128 + c]);
    return;
  }
  idx -= 32768;
  if (idx < 98304) {  // EWtR: 6 stages [k=128][c=128] -> [c][k], rows 256B
    int s = idx >> 14, r = idx & 16383, k = r >> 7, c = r & 127;
    *(unsigned short*)(ws + EWTR_OFF + (unsigned long long)s * 32768 +
                       c * 256 + ((k * 2) ^ ((c & 15) << 4))) = f2bf(We_res[s * 16384 + k * 128 + c]);
    return;
  }
  idx -= 98304;
  if (idx < 8192) {  // W2FR
    int w = idx >> 10, h = (idx >> 9) & 1, lane = (idx >> 3) & 63, e = idx & 7;
    int c = w * 32 + h * 16 + (lane & 15);
    int k = (lane >> 4) * 8 + e;
    float v = (k < 16) ? Wf_rbf[k * 256 + c] * Wf_out[c] : 0.f;
    *(unsigned short*)(ws + W2F_OFF + (unsigned)idx * 2) = f2bf(v);
    return;
  }
  idx -= 8192;
  if (idx < 8192) {  // W2E: We_rbf^T, k padded (scatter kernel layout)
    int c = idx >> 5, k = idx & 31;
    float v = (k < 16) ? We_rbf[k * 256 + c] : 0.f;
    *(unsigned short*)(ws + W2E_OFF + c * 64 + ((k * 2) ^ ((c & 3) << 4))) = f2bf(v);
  }
}

// =====================================================================
// scatter: xE[id_j[e]] += m[e] .* (rbf[e] @ We_rbf)   (f32 atomics)
// =====================================================================
__global__ __launch_bounds__(256) void scatter_kernel(
    const float* __restrict__ m, const float* __restrict__ rbf,
    const int* __restrict__ id_j, const char* __restrict__ W2E,
    float* __restrict__ xE, int nE) {
  __shared__ char rbfA[8192];   // [128][32] bf16, swizzled (row&3)<<4
  __shared__ char wb[16384];    // W2E staged
  __shared__ int sI[128];
  const int tid = threadIdx.x;
  const int lane = tid & 63, q = lane >> 4, r15 = lane & 15;
  const int wid = tid >> 6, wrow = wid * 32;
  const long long row0 = (long long)blockIdx.x * 128;
  const f32x4 zf = {0.f, 0.f, 0.f, 0.f};

#pragma unroll
  for (int i = 0; i < 8; ++i) {
    const int idx = tid * 8 + i;
    const int row = idx >> 4, d = idx & 15;
    long long rg = row0 + row; if (rg >= nE) rg = nE - 1;
    *(unsigned short*)(rbfA + row * 64 + ((d * 2) ^ ((row & 3) << 4))) = f2bf(rbf[rg * 16 + d]);
    *(unsigned short*)(rbfA + row * 64 + (((16 + d) * 2) ^ ((row & 3) << 4))) = 0;
  }
  if (tid < 128) {
    long long rg = row0 + tid;
    sI[tid] = (rg < nE) ? id_j[rg] : -1;
  }
#pragma unroll
  for (int i = 0; i < 4; ++i) gl16(W2E + i * 4096 + tid * 16, wb + i * 4096 + tid * 16);
  asm volatile("s_waitcnt vmcnt(0)" ::: "memory");
  __syncthreads();

  bf16x8 ar[2];
#pragma unroll
  for (int fr = 0; fr < 2; ++fr) {
    const int row = wrow + fr * 16 + r15;
    ar[fr] = *(const bf16x8*)(rbfA + row * 64 + ((q * 16) ^ ((row & 3) << 4)));
  }
#pragma unroll
  for (int fcg = 0; fcg < 16; ++fcg) {
    const int ci = fcg * 16 + r15;
    bf16x8 bw = *(const bf16x8*)(wb + ci * 64 + ((q * 16) ^ ((ci & 3) << 4)));
#pragma unroll
    for (int fr = 0; fr < 2; ++fr) {
      f32x4 rw = __builtin_amdgcn_mfma_f32_16x16x32_bf16(ar[fr], bw, zf, 0, 0, 0);
      const int col = fcg * 16 + r15;
#pragma unroll
      for (int j = 0; j < 4; ++j) {
        const int rowl = wrow + fr * 16 + q * 4 + j;
        const int aid = sI[rowl];
        if (aid >= 0) {
          const long long rg = row0 + rowl;
          float mv = m[rg * 256 + col];
          atomicAdd(&xE[(long long)aid * 256 + col], mv * rw[j]);
        }
      }
    }
  }
}

// =====================================================================
// force (column-sliced): 6250 blocks x 512 thr; block = 64 rows.
// Wave wid owns cols 32*wid..+31; W-slice in 64 VGPRs (global->regs,
// coalesced FWR layout). X double-buffered in LDS; y written once/elem.
// xs = lane-local residual checkpoint (16 regs).
// =====================================================================
__global__ __launch_bounds__(512) void force_kernel(
    const float* __restrict__ m, const float* __restrict__ rbf,
    const char* __restrict__ FWR, const char* __restrict__ W2FR,
    float* __restrict__ Fout, int nE) {
  __shared__ char Xbuf[2][32768];  // [64 rows][512B], swz key (row&15)<<4
  __shared__ char rbfls[4096];     // [64 rows][64B] bf16 k-padded, swz (row&3)<<4
  __shared__ float Fp[8][64];      // per-wave partial F
  const int tid = threadIdx.x;
  const int lane = tid & 63, q = lane >> 4, r15 = lane & 15;
  const int wid = tid >> 6;        // col-slice owner: cols 32*wid..+31
  const long long row0 = (long long)blockIdx.x * 64;
  const f32x4 zf = {0.f, 0.f, 0.f, 0.f};

  // ---- prologue: m -> X[0] (bf16, swizzled), rbf -> rbfls ----
  {
    const int row = tid >> 3, cb = tid & 7;
    long long rg = row0 + row; if (rg >= nE) rg = nE - 1;
    const float* mp = m + rg * 256 + cb * 32;
    const int key = (row & 15) << 4;
#pragma unroll
    for (int i = 0; i < 8; ++i) {
      float4 v = *(const float4*)(mp + i * 4);
      u32x2 p;
      p[0] = (unsigned)f2bf(v.x) | ((unsigned)f2bf(v.y) << 16);
      p[1] = (unsigned)f2bf(v.z) | ((unsigned)f2bf(v.w) << 16);
      *(u32x2*)(Xbuf[0] + row * 512 + (((cb * 32 + i * 4) * 2) ^ key)) = p;
    }
    const int d2 = cb * 2;
    float ra = rbf[rg * 16 + d2], rb = rbf[rg * 16 + d2 + 1];
    const int rkey = (row & 3) << 4;
    *(unsigned*)(rbfls + row * 64 + ((d2 * 2) ^ rkey)) =
        (unsigned)f2bf(ra) | ((unsigned)f2bf(rb) << 16);
    *(unsigned*)(rbfls + row * 64 + (((16 + d2) * 2) ^ rkey)) = 0u;  // k pad
  }
  __syncthreads();

  bf16x8 W[2][8];          // wave's W-slice fragments (64 VGPRs)
  unsigned xs[4][2][2];    // residual checkpoint: [rt][h][pair of 2 bf16]

  for (int s = 0; s < 7; ++s) {
    // load W-slice for this stage: coalesced (1KB per instr per wave)
    const char* wbase = FWR + (unsigned long long)s * 131072 + wid * 16384;
#pragma unroll
    for (int h = 0; h < 2; ++h)
#pragma unroll
      for (int ks = 0; ks < 8; ++ks)
        W[h][ks] = *(const bf16x8*)(wbase + h * 8192 + ks * 1024 + lane * 16);

    const int cur = s & 1;
    const char* Xr = (const char*)Xbuf + cur * 32768;
    char* Xw = (char*)Xbuf + (cur ^ 1) * 32768;
    const bool isS0 = (s == 0);
    const bool isRes = (s >= 2) && !(s & 1);

#pragma unroll
    for (int rt = 0; rt < 4; ++rt) {
      const int row = rt * 16 + r15;
      const int key = (row & 15) << 4;
      f32x4 a0 = zf, a1 = zf;
#pragma unroll
      for (int ks = 0; ks < 8; ++ks) {
        bf16x8 b = *(const bf16x8*)(Xr + row * 512 + ((ks * 64 + q * 16) ^ key));
        a0 = __builtin_amdgcn_mfma_f32_16x16x32_bf16(W[0][ks], b, a0, 0, 0, 0);
        a1 = __builtin_amdgcn_mfma_f32_16x16x32_bf16(W[1][ks], b, a1, 0, 0, 0);
      }
#pragma unroll
      for (int h = 0; h < 2; ++h) {
        const f32x4 acc = h ? a1 : a0;
        float o0 = ssilu(acc[0]), o1 = ssilu(acc[1]);
        float o2 = ssilu(acc[2]), o3 = ssilu(acc[3]);
        if (isRes) {
          const unsigned p0 = xs[rt][h][0], p1 = xs[rt][h][1];
          o0 = (bf2f((unsigned short)(p0 & 0xffff)) + o0) * INV_SQRT2;
          o1 = (bf2f((unsigned short)(p0 >> 16)) + o1) * INV_SQRT2;
          o2 = (bf2f((unsigned short)(p1 & 0xffff)) + o2) * INV_SQRT2;
          o3 = (bf2f((unsigned short)(p1 >> 16)) + o3) * INV_SQRT2;
        }
        const unsigned h01 = (unsigned)f2bf(o0) | ((unsigned)f2bf(o1) << 16);
        const unsigned h23 = (unsigned)f2bf(o2) | ((unsigned)f2bf(o3) << 16);
        if (isS0 | isRes) { xs[rt][h][0] = h01; xs[rt][h][1] = h23; }
        if (s < 6) {
          // y cols c0..c0+3 (c0 = 32*wid + 16h + 4q), row = own row
          u32x2 p; p[0] = h01; p[1] = h23;
          *(u32x2*)(Xw + row * 512 + (((wid * 32 + h * 16 + q * 4) * 2) ^ key)) = p;
        }
      }
    }
    __syncthreads();
  }

  // ---- final: rw = rbf @ (Wf_rbf .* Wf_out) slice; F partial = x6 . rw ----
  bf16x8 A2[2];
#pragma unroll
  for (int h = 0; h < 2; ++h)
    A2[h] = *(const bf16x8*)(W2FR + wid * 2048 + h * 1024 + lane * 16);

  float part[4];
#pragma unroll
  for (int rt = 0; rt < 4; ++rt) {
    const int row = rt * 16 + r15;
    bf16x8 br = *(const bf16x8*)(rbfls + row * 64 + ((q * 16) ^ ((row & 3) << 4)));
    float p = 0.f;
#pragma unroll
    for (int h = 0; h < 2; ++h) {
      f32x4 rw = __builtin_amdgcn_mfma_f32_16x16x32_bf16(A2[h], br, zf, 0, 0, 0);
      const unsigned p0 = xs[rt][h][0], p1 = xs[rt][h][1];
      p += bf2f((unsigned short)(p0 & 0xffff)) * rw[0]
         + bf2f((unsigned short)(p0 >> 16)) * rw[1]
         + bf2f((unsigned short)(p1 & 0xffff)) * rw[2]
         + bf2f((unsigned short)(p1 >> 16)) * rw[3];
    }
    part[rt] = p;
  }
#pragma unroll
  for (int rt = 0; rt < 4; ++rt) {
    part[rt] += __shfl_xor(part[rt], 16, 64);
    part[rt] += __shfl_xor(part[rt], 32, 64);
  }
  if (q == 0) {
#pragma unroll
    for (int rt = 0; rt < 4; ++rt) Fp[wid][rt * 16 + r15] = part[rt];
  }
  __syncthreads();
  if (tid < 64) {
    float sum = 0.f;
#pragma unroll
    for (int w = 0; w < 8; ++w) sum += Fp[w][tid];
    const long long r = row0 + tid;
    if (r < nE) Fout[r] = sum;
  }
}

// =====================================================================
// energy MLP: xE[25000][256] -> ssilu(@We_in[256x128]) -> 3 residual(128) -> @We_out
// (small: 196 blocks; unchanged)
// =====================================================================
__global__ __launch_bounds__(256) void energy_kernel(
    const float* __restrict__ xE, const char* __restrict__ EWt0,
    const char* __restrict__ EWtR, const float* __restrict__ We_out,
    float* __restrict__ Eout, int nA) {
  __shared__ char xbuf[32768];  // [128][256B], swz key (row&15)<<4
  __shared__ char wbuf[16384];
  const int tid = threadIdx.x;
  const int lane = tid & 63, q = lane >> 4, r15 = lane & 15;
  const int wid = tid >> 6, wrow = wid * 32;
  const long long row0 = (long long)blockIdx.x * 128;
  const f32x4 zf = {0.f, 0.f, 0.f, 0.f};

  bf16x8 a[2][8];
  unsigned xs[4][2][2][2];

#pragma unroll
  for (int fr = 0; fr < 2; ++fr) {
#pragma unroll
    for (int ks = 0; ks < 8; ++ks) {
      long long rg = row0 + wrow + fr * 16 + r15;
      bf16x8 t = {0, 0, 0, 0, 0, 0, 0, 0};
      if (rg < nA) {
        const float* p = xE + rg * 256 + ks * 32 + q * 8;
        float4 v0 = *(const float4*)p;
        float4 v1 = *(const float4*)(p + 4);
        t[0] = (short)f2bf(v0.x); t[1] = (short)f2bf(v0.y);
        t[2] = (short)f2bf(v0.z); t[3] = (short)f2bf(v0.w);
        t[4] = (short)f2bf(v1.x); t[5] = (short)f2bf(v1.y);
        t[6] = (short)f2bf(v1.z); t[7] = (short)f2bf(v1.w);
      }
      a[fr][ks] = t;
    }
  }

  for (int s = 0; s < 7; ++s) {
    const int K2 = (s == 0) ? 512 : 256;  // bytes per weight row
    const int wchunk = 32 * K2;
    const int nld = wchunk >> 12;         // 4 or 2 16B-loads per thread
    const char* wsrc = (s == 0) ? EWt0 : (EWtR + (unsigned long long)(s - 1) * 32768);
    const int isS0 = (s == 0);
    const int isRes = (s >= 2) && ((s & 1) == 0);
#pragma unroll
    for (int c = 0; c < 4; ++c) {
      for (int i = 0; i < nld; ++i)
        gl16(wsrc + c * wchunk + i * 4096 + tid * 16, wbuf + i * 4096 + tid * 16);
      asm volatile("s_waitcnt vmcnt(0)" ::: "memory");
      __syncthreads();

      f32x4 acc[2][2] = {{zf, zf}, {zf, zf}};
      if (s == 0) {
#pragma unroll
        for (int ks = 0; ks < 8; ++ks) {
          const int kb = ks * 64 + q * 16;
          const int ci0 = r15, ci1 = 16 + r15;
          bf16x8 b0 = *(const bf16x8*)(wbuf + ci0 * 512 + (kb ^ ((ci0 & 15) << 4)));
          bf16x8 b1 = *(const bf16x8*)(wbuf + ci1 * 512 + (kb ^ ((ci1 & 15) << 4)));
          acc[0][0] = __builtin_amdgcn_mfma_f32_16x16x32_bf16(a[0][ks], b0, acc[0][0], 0, 0, 0);
          acc[1][0] = __builtin_amdgcn_mfma_f32_16x16x32_bf16(a[1][ks], b0, acc[1][0], 0, 0, 0);
          acc[0][1] = __builtin_amdgcn_mfma_f32_16x16x32_bf16(a[0][ks], b1, acc[0][1], 0, 0, 0);
          acc[1][1] = __builtin_amdgcn_mfma_f32_16x16x32_bf16(a[1][ks], b1, acc[1][1], 0, 0, 0);
        }
      } else {
#pragma unroll
        for (int ks = 0; ks < 4; ++ks) {
          const int kb = ks * 64 + q * 16;
          const int ci0 = r15, ci1 = 16 + r15;
          bf16x8 b0 = *(const bf16x8*)(wbuf + ci0 * 256 + (kb ^ ((ci0 & 15) << 4)));
          bf16x8 b1 = *(const bf16x8*)(wbuf + ci1 * 256 + (kb ^ ((ci1 & 15) << 4)));
          acc[0][0] = __builtin_amdgcn_mfma_f32_16x16x32_bf16(a[0][ks], b0, acc[0][0], 0, 0, 0);
          acc[1][0] = __builtin_amdgcn_mfma_f32_16x16x32_bf16(a[1][ks], b0, acc[1][0], 0, 0, 0);
          acc[0][1] = __builtin_amdgcn_mfma_f32_16x16x32_bf16(a[0][ks], b1, acc[0][1], 0, 0, 0);
          acc[1][1] = __builtin_amdgcn_mfma_f32_16x16x32_bf16(a[1][ks], b1, acc[1][1], 0, 0, 0);
        }
      }
#pragma unroll
      for (int fr = 0; fr < 2; ++fr) {
#pragma unroll
        for (int fc = 0; fc < 2; ++fc) {
          float o0 = ssilu(acc[fr][fc][0]), o1 = ssilu(acc[fr][fc][1]);
          float o2 = ssilu(acc[fr][fc][2]), o3 = ssilu(acc[fr][fc][3]);
          if (isRes) {
            const unsigned p0 = xs[c][fr][fc][0], p1 = xs[c][fr][fc][1];
            o0 = (bf2f((unsigned short)(p0 & 0xffff)) + o0) * INV_SQRT2;
            o1 = (bf2f((unsigned short)(p0 >> 16)) + o1) * INV_SQRT2;
            o2 = (bf2f((unsigned short)(p1 & 0xffff)) + o2) * INV_SQRT2;
            o3 = (bf2f((unsigned short)(p1 >> 16)) + o3) * INV_SQRT2;
          }
          const unsigned short h0 = f2bf(o0), h1 = f2bf(o1), h2 = f2bf(o2), h3 = f2bf(o3);
          if (isS0 | isRes) {
            xs[c][fr][fc][0] = (unsigned)h0 | ((unsigned)h1 << 16);
            xs[c][fr][fc][1] = (unsigned)h2 | ((unsigned)h3 << 16);
          }
          if (s < 6) {
            const int colb = (c * 32 + fc * 16 + r15) * 2;
            const int rb = wrow + fr * 16 + q * 4;
            *(unsigned short*)(xbuf + (rb + 0) * 256 + (colb ^ (((rb + 0) & 15) << 4))) = h0;
            *(unsigned short*)(xbuf + (rb + 1) * 256 + (colb ^ (((rb + 1) & 15) << 4))) = h1;
            *(unsigned short*)(xbuf + (rb + 2) * 256 + (colb ^ (((rb + 2) & 15) << 4))) = h2;
            *(unsigned short*)(xbuf + (rb + 3) * 256 + (colb ^ (((rb + 3) & 15) << 4))) = h3;
          }
        }
      }
      __syncthreads();
    }
    if (s < 6) {
#pragma unroll
      for (int fr = 0; fr < 2; ++fr) {
#pragma unroll
        for (int ks = 0; ks < 4; ++ks) {
          const int row = wrow + fr * 16 + r15;
          const int kb = ks * 64 + q * 16;
          a[fr][ks] = *(const bf16x8*)(xbuf + row * 256 + (kb ^ (r15 << 4)));
        }
      }
      __syncthreads();
    }
  }

  // final: E[row] = sum_c x[row,c] * We_out[c]
  float psum[2][4] = {{0.f, 0.f, 0.f, 0.f}, {0.f, 0.f, 0.f, 0.f}};
#pragma unroll
  for (int c = 0; c < 4; ++c) {
#pragma unroll
    for (int f = 0; f < 2; ++f) {
      const int col = c * 32 + f * 16 + r15;
      const float wo = We_out[col];
#pragma unroll
      for (int fr = 0; fr < 2; ++fr) {
        const unsigned p0 = xs[c][fr][f][0], p1 = xs[c][fr][f][1];
        psum[fr][0] += bf2f((unsigned short)(p0 & 0xffff)) * wo;
        psum[fr][1] += bf2f((unsigned short)(p0 >> 16)) * wo;
        psum[fr][2] += bf2f((unsigned short)(p1 & 0xffff)) * wo;
        psum[fr][3] += bf2f((unsigned short)(p1 >> 16)) * wo;
      }
    }
  }
#pragma unroll
  for (int off = 1; off < 16; off <<= 1) {
#pragma unroll
    for (int fr = 0; fr < 2; ++fr) {
#pragma unroll
      for (int j = 0; j < 4; ++j) psum[fr][j] += __shfl_xor(psum[fr][j], off, 64);
    }
  }
  if (r15 == 0) {
#pragma unroll
    for (int fr = 0; fr < 2; ++fr) {
#pragma unroll
      for (int j = 0; j < 4; ++j) {
        const long long rg = row0 + wrow + fr * 16 + q * 4 + j;
        if (rg < nA) Eout[rg] = psum[fr][j];
      }
    }
  }
}

// =====================================================================
extern "C" void kernel_launch(void* const* d_in, const int* in_sizes, int n_in,
                              void* d_out, int out_size, void* d_ws, size_t ws_size,
                              hipStream_t stream) {
  const float* m      = (const float*)d_in[1];
  const float* rbf    = (const float*)d_in[2];
  const int*   id_j   = (const int*)d_in[3];
  const float* We_rbf = (const float*)d_in[4];
  const float* We_in  = (const float*)d_in[5];
  const float* We_res = (const float*)d_in[6];
  const float* We_out = (const float*)d_in[7];
  const float* Wf_rbf = (const float*)d_in[8];
  const float* Wf_in  = (const float*)d_in[9];
  const float* Wf_res = (const float*)d_in[10];
  const float* Wf_out = (const float*)d_in[11];
  const int nA = in_sizes[0] / 128;   // 25000
  const int nE = in_sizes[1] / 256;   // 400000

  char* ws = (char*)d_ws;
  float* xE = (float*)(ws + XE_OFF);
  float* Eout = (float*)d_out;
  float* Fout = Eout + nA;

  prep_kernel<<<2368, 256, 0, stream>>>(We_rbf, We_in, We_res, Wf_rbf, Wf_in, Wf_res, Wf_out, ws);
  hipMemsetAsync(xE, 0, (size_t)nA * 256 * 4, stream);
  scatter_kernel<<<(nE + 127) / 128, 256, 0, stream>>>(m, rbf, id_j, ws + W2E_OFF, xE, nE);
  energy_kernel<<<(nA + 127) / 128, 256, 0, stream>>>(xE, ws + EWT0_OFF, ws + EWTR_OFF, We_out, Eout, nA);
  force_kernel<<<(nE + 63) / 64, 512, 0, stream>>>(m, rbf, ws + FWT_OFF, ws + W2F_OFF, Fout, nE);
}

// Round 8
// 1007.289 us; speedup vs baseline: 1.4057x; 1.0938x over previous
//
#include <hip/hip_runtime.h>
#include <stdint.h>

// GemNet OutputBlock fused kernels for MI355X (gfx950).
// E = MLP(segment_sum(m .* (rbf@We_rbf))) @ We_out
// F = (ResMLP(ssilu(m@Wf_in)) .* (rbf@Wf_rbf)) @ Wf_out
//
// R8 changes vs R7 (force_kernel):
//  - 4-wave blocks (256 thr), 64 cols/wave: W[4][8]=128 regs; each X b128
//    read feeds 4 MFMAs (was 2) -> LDS read traffic per CU halves.
//  - Total regs ~230 (129-256 band, 8 waves/CU) = TWO independent 4-wave
//    blocks per CU -> decoupled barriers/W-loads cross-hide stalls (R7 had
//    one 8-wave barrier-locked block; 743us vs ~30k-cyc floor = latency).
//  - __launch_bounds__(256,2): total<=256; arch demand ~100 (W/acc AGPR-able).
//  - LDS 66.5KB (2x32KB X dbuf + Fp); rbf gating loads global->reg in final.

typedef __attribute__((ext_vector_type(8))) short bf16x8;
typedef __attribute__((ext_vector_type(4))) float f32x4;
typedef __attribute__((ext_vector_type(2))) unsigned u32x2;
typedef __attribute__((ext_vector_type(4))) unsigned u32x4;

#define INV_SQRT2 0.7071067811865476f

// ---- workspace layout (bytes) ----
#define XE_OFF     0ull
#define XE_BYTES   25600000ull                 // xE f32 [25000][256]
#define FWT_OFF    (XE_OFF + XE_BYTES)
#define FWT_BYTES  917504ull                   // FWR: 7 x [4 w][4 h][8 ks][64 lane]x16B
#define EWT0_OFF   (FWT_OFF + FWT_BYTES)
#define EWT0_BYTES 65536ull                    // [128][256] bf16
#define EWTR_OFF   (EWT0_OFF + EWT0_BYTES)
#define EWTR_BYTES 196608ull                   // 6 x [128][128] bf16
#define W2F_OFF    (EWTR_OFF + EWTR_BYTES)
#define W2F_BYTES  16384ull                    // W2FR: [4 w][4 h][64 lane]x16B
#define W2E_OFF    (W2F_OFF + W2F_BYTES)
#define W2E_BYTES  16384ull                    // We_rbf^T [256][32] bf16 (k padded)

static __device__ __forceinline__ unsigned short f2bf(float f) {
  union { float f; unsigned u; } v; v.f = f;
  return (unsigned short)((v.u + 0x7fffu + ((v.u >> 16) & 1u)) >> 16);
}
static __device__ __forceinline__ float bf2f(unsigned short h) {
  union { unsigned u; float f; } v; v.u = ((unsigned)h) << 16;
  return v.f;
}
static __device__ __forceinline__ float ssilu(float x) {
  // silu(x)/0.6 = x * sigmoid(x) * 5/3
  return 1.6666666666666667f * x * __builtin_amdgcn_rcpf(1.0f + __expf(-x));
}
static __device__ __forceinline__ void gl16(const void* g, void* l) {
  __builtin_amdgcn_global_load_lds(
      (const __attribute__((address_space(1))) void*)(unsigned long long)(uintptr_t)g,
      (__attribute__((address_space(3))) void*)(unsigned)(uintptr_t)l, 16, 0, 0);
}

// =====================================================================
// prep: weights f32 -> bf16 into frag-ready layouts.
//  FWR  (force chain): [s][w][h][ks][lane]x16B; c = 64w+16h+(lane&15),
//    k = 32ks+8*(lane>>4)+e  -> W_s[k][c]
//  W2FR (force gating): [w][h][lane]x16B; k = 8*(lane>>4)+e (pad k>=16)
//  EWt0/EWtR (energy, LDS-staged path): [c][k] XOR-swizzled, unchanged.
//  W2E (scatter): unchanged.
// =====================================================================
__global__ void prep_kernel(const float* __restrict__ We_rbf,
                            const float* __restrict__ We_in,
                            const float* __restrict__ We_res,
                            const float* __restrict__ Wf_rbf,
                            const float* __restrict__ Wf_in,
                            const float* __restrict__ Wf_res,
                            const float* __restrict__ Wf_out,
                            char* __restrict__ ws) {
  int idx = blockIdx.x * 256 + threadIdx.x;
  if (idx < 458752) {  // FWR
    int s = idx >> 16, r = idx & 65535;
    int w = r >> 14, h = (r >> 12) & 3, ks = (r >> 9) & 7, lane = (r >> 3) & 63, e = r & 7;
    int c = w * 64 + h * 16 + (lane & 15);
    int k = ks * 32 + (lane >> 4) * 8 + e;
    float v = (s == 0) ? Wf_in[k * 256 + c] : Wf_res[(s - 1) * 65536 + k * 256 + c];
    *(unsigned short*)(ws + FWT_OFF + (unsigned long long)s * 131072 + (unsigned)r * 2) = f2bf(v);
    return;
  }
  idx -= 458752;
  if (idx < 32768) {  // EWt0: [k=256][c=128] -> [c][k]
    int k = idx >> 7, c = idx & 127;
    *(unsigned short*)(ws + EWT0_OFF + c * 512 + ((k * 2) ^ ((c & 15) << 4))) = f2bf(We_in[k * 128 + c]);
    return;
  }
  idx -= 32768;
  if (idx < 98304) {  // EWtR: 6 stages [k=128][c=128] -> [c][k], rows 256B
    int s = idx >> 14, r = idx & 16383, k = r >> 7, c = r & 127;
    *(unsigned short*)(ws + EWTR_OFF + (unsigned long long)s * 32768 +
                       c * 256 + ((k * 2) ^ ((c & 15) << 4))) = f2bf(We_res[s * 16384 + k * 128 + c]);
    return;
  }
  idx -= 98304;
  if (idx < 8192) {  // W2FR
    int w = idx >> 11, h = (idx >> 9) & 3, lane = (idx >> 3) & 63, e = idx & 7;
    int c = w * 64 + h * 16 + (lane & 15);
    int k = (lane >> 4) * 8 + e;
    float v = (k < 16) ? Wf_rbf[k * 256 + c] * Wf_out[c] : 0.f;
    *(unsigned short*)(ws + W2F_OFF + (unsigned)idx * 2) = f2bf(v);
    return;
  }
  idx -= 8192;
  if (idx < 8192) {  // W2E: We_rbf^T, k padded (scatter kernel layout)
    int c = idx >> 5, k = idx & 31;
    float v = (k < 16) ? We_rbf[k * 256 + c] : 0.f;
    *(unsigned short*)(ws + W2E_OFF + c * 64 + ((k * 2) ^ ((c & 3) << 4))) = f2bf(v);
  }
}

// =====================================================================
// scatter: xE[id_j[e]] += m[e] .* (rbf[e] @ We_rbf)   (f32 atomics)
// =====================================================================
__global__ __launch_bounds__(256) void scatter_kernel(
    const float* __restrict__ m, const float* __restrict__ rbf,
    const int* __restrict__ id_j, const char* __restrict__ W2E,
    float* __restrict__ xE, int nE) {
  __shared__ char rbfA[8192];   // [128][32] bf16, swizzled (row&3)<<4
  __shared__ char wb[16384];    // W2E staged
  __shared__ int sI[128];
  const int tid = threadIdx.x;
  const int lane = tid & 63, q = lane >> 4, r15 = lane & 15;
  const int wid = tid >> 6, wrow = wid * 32;
  const long long row0 = (long long)blockIdx.x * 128;
  const f32x4 zf = {0.f, 0.f, 0.f, 0.f};

#pragma unroll
  for (int i = 0; i < 8; ++i) {
    const int idx = tid * 8 + i;
    const int row = idx >> 4, d = idx & 15;
    long long rg = row0 + row; if (rg >= nE) rg = nE - 1;
    *(unsigned short*)(rbfA + row * 64 + ((d * 2) ^ ((row & 3) << 4))) = f2bf(rbf[rg * 16 + d]);
    *(unsigned short*)(rbfA + row * 64 + (((16 + d) * 2) ^ ((row & 3) << 4))) = 0;
  }
  if (tid < 128) {
    long long rg = row0 + tid;
    sI[tid] = (rg < nE) ? id_j[rg] : -1;
  }
#pragma unroll
  for (int i = 0; i < 4; ++i) gl16(W2E + i * 4096 + tid * 16, wb + i * 4096 + tid * 16);
  asm volatile("s_waitcnt vmcnt(0)" ::: "memory");
  __syncthreads();

  bf16x8 ar[2];
#pragma unroll
  for (int fr = 0; fr < 2; ++fr) {
    const int row = wrow + fr * 16 + r15;
    ar[fr] = *(const bf16x8*)(rbfA + row * 64 + ((q * 16) ^ ((row & 3) << 4)));
  }
#pragma unroll
  for (int fcg = 0; fcg < 16; ++fcg) {
    const int ci = fcg * 16 + r15;
    bf16x8 bw = *(const bf16x8*)(wb + ci * 64 + ((q * 16) ^ ((ci & 3) << 4)));
#pragma unroll
    for (int fr = 0; fr < 2; ++fr) {
      f32x4 rw = __builtin_amdgcn_mfma_f32_16x16x32_bf16(ar[fr], bw, zf, 0, 0, 0);
      const int col = fcg * 16 + r15;
#pragma unroll
      for (int j = 0; j < 4; ++j) {
        const int rowl = wrow + fr * 16 + q * 4 + j;
        const int aid = sI[rowl];
        if (aid >= 0) {
          const long long rg = row0 + rowl;
          float mv = m[rg * 256 + col];
          atomicAdd(&xE[(long long)aid * 256 + col], mv * rw[j]);
        }
      }
    }
  }
}

// =====================================================================
// force (column-sliced, R8): 6250 blocks x 256 thr (4 waves); block = 64 rows.
// Wave wid owns cols 64*wid..+63; W[4][8] = 128 regs (global->regs, FWR
// layout). X double-buffered 2x32KB; each X b128 read feeds 4 MFMAs.
// xs = lane-local residual checkpoint (32 regs). 2 blocks/CU co-resident.
// =====================================================================
__global__ __launch_bounds__(256, 2) void force_kernel(
    const float* __restrict__ m, const float* __restrict__ rbf,
    const char* __restrict__ FWR, const char* __restrict__ W2FR,
    float* __restrict__ Fout, int nE) {
  __shared__ char Xbuf[2][32768];  // [64 rows][512B], swz key (row&15)<<4
  __shared__ float Fp[4][64];      // per-wave partial F
  const int tid = threadIdx.x;
  const int lane = tid & 63, q = lane >> 4, r15 = lane & 15;
  const int wid = tid >> 6;        // 0..3: cols 64*wid..+63
  const long long row0 = (long long)blockIdx.x * 64;
  const f32x4 zf = {0.f, 0.f, 0.f, 0.f};

  // ---- prologue: m -> X[0] (bf16, swizzled) ----
  {
    const int row = tid >> 2, c0 = (tid & 3) * 64;
    long long rg = row0 + row; if (rg >= nE) rg = nE - 1;
    const float* mp = m + rg * 256 + c0;
    const int key = (row & 15) << 4;
#pragma unroll
    for (int i = 0; i < 8; ++i) {
      float4 v0 = *(const float4*)(mp + i * 8);
      float4 v1 = *(const float4*)(mp + i * 8 + 4);
      u32x4 p;
      p[0] = (unsigned)f2bf(v0.x) | ((unsigned)f2bf(v0.y) << 16);
      p[1] = (unsigned)f2bf(v0.z) | ((unsigned)f2bf(v0.w) << 16);
      p[2] = (unsigned)f2bf(v1.x) | ((unsigned)f2bf(v1.y) << 16);
      p[3] = (unsigned)f2bf(v1.z) | ((unsigned)f2bf(v1.w) << 16);
      *(u32x4*)(Xbuf[0] + row * 512 + (((c0 + i * 8) * 2) ^ key)) = p;
    }
  }
  __syncthreads();

  bf16x8 W[4][8];          // wave's 64-col W-slice (128 VGPRs/AGPRs)
  unsigned xs[4][4][2];    // residual checkpoint: [rt][h][pair of 2 bf16]

  for (int s = 0; s < 7; ++s) {
    const char* wbase = FWR + (unsigned long long)s * 131072 + wid * 32768;
#pragma unroll
    for (int h = 0; h < 4; ++h)
#pragma unroll
      for (int ks = 0; ks < 8; ++ks)
        W[h][ks] = *(const bf16x8*)(wbase + h * 8192 + ks * 1024 + lane * 16);

    const int cur = s & 1;
    const char* Xr = (const char*)Xbuf + cur * 32768;
    char* Xw = (char*)Xbuf + (cur ^ 1) * 32768;
    const bool isS0 = (s == 0);
    const bool isRes = (s >= 2) && !(s & 1);

#pragma unroll
    for (int rt = 0; rt < 4; ++rt) {
      const int row = rt * 16 + r15;
      const int key = (row & 15) << 4;
      f32x4 a[4] = {zf, zf, zf, zf};
#pragma unroll
      for (int ks = 0; ks < 8; ++ks) {
        bf16x8 b = *(const bf16x8*)(Xr + row * 512 + ((ks * 64 + q * 16) ^ key));
        a[0] = __builtin_amdgcn_mfma_f32_16x16x32_bf16(W[0][ks], b, a[0], 0, 0, 0);
        a[1] = __builtin_amdgcn_mfma_f32_16x16x32_bf16(W[1][ks], b, a[1], 0, 0, 0);
        a[2] = __builtin_amdgcn_mfma_f32_16x16x32_bf16(W[2][ks], b, a[2], 0, 0, 0);
        a[3] = __builtin_amdgcn_mfma_f32_16x16x32_bf16(W[3][ks], b, a[3], 0, 0, 0);
      }
#pragma unroll
      for (int h = 0; h < 4; ++h) {
        float o0 = ssilu(a[h][0]), o1 = ssilu(a[h][1]);
        float o2 = ssilu(a[h][2]), o3 = ssilu(a[h][3]);
        if (isRes) {
          const unsigned p0 = xs[rt][h][0], p1 = xs[rt][h][1];
          o0 = (bf2f((unsigned short)(p0 & 0xffff)) + o0) * INV_SQRT2;
          o1 = (bf2f((unsigned short)(p0 >> 16)) + o1) * INV_SQRT2;
          o2 = (bf2f((unsigned short)(p1 & 0xffff)) + o2) * INV_SQRT2;
          o3 = (bf2f((unsigned short)(p1 >> 16)) + o3) * INV_SQRT2;
        }
        const unsigned h01 = (unsigned)f2bf(o0) | ((unsigned)f2bf(o1) << 16);
        const unsigned h23 = (unsigned)f2bf(o2) | ((unsigned)f2bf(o3) << 16);
        if (isS0 | isRes) { xs[rt][h][0] = h01; xs[rt][h][1] = h23; }
        if (s < 6) {
          // y cols c0..c0+3 (c0 = 64*wid + 16h + 4q), row = own row
          u32x2 p; p[0] = h01; p[1] = h23;
          *(u32x2*)(Xw + row * 512 + (((wid * 64 + h * 16 + q * 4) * 2) ^ key)) = p;
        }
      }
    }
    __syncthreads();
  }

  // ---- final: rw = rbf @ (Wf_rbf .* Wf_out) slice; F partial = x6 . rw ----
  bf16x8 A2[4];
#pragma unroll
  for (int h = 0; h < 4; ++h)
    A2[h] = *(const bf16x8*)(W2FR + wid * 4096 + h * 1024 + lane * 16);

  float part[4];
#pragma unroll
  for (int rt = 0; rt < 4; ++rt) {
    const int row = rt * 16 + r15;
    long long rg = row0 + row; if (rg >= nE) rg = nE - 1;
    bf16x8 br = {0, 0, 0, 0, 0, 0, 0, 0};
    if (q < 2) {  // B-frag k = q*8+e (<16); k>=16 padded zero
      const float* p = rbf + rg * 16 + q * 8;
      float4 v0 = *(const float4*)p;
      float4 v1 = *(const float4*)(p + 4);
      br[0] = (short)f2bf(v0.x); br[1] = (short)f2bf(v0.y);
      br[2] = (short)f2bf(v0.z); br[3] = (short)f2bf(v0.w);
      br[4] = (short)f2bf(v1.x); br[5] = (short)f2bf(v1.y);
      br[6] = (short)f2bf(v1.z); br[7] = (short)f2bf(v1.w);
    }
    float p = 0.f;
#pragma unroll
    for (int h = 0; h < 4; ++h) {
      f32x4 rw = __builtin_amdgcn_mfma_f32_16x16x32_bf16(A2[h], br, zf, 0, 0, 0);
      const unsigned p0 = xs[rt][h][0], p1 = xs[rt][h][1];
      p += bf2f((unsigned short)(p0 & 0xffff)) * rw[0]
         + bf2f((unsigned short)(p0 >> 16)) * rw[1]
         + bf2f((unsigned short)(p1 & 0xffff)) * rw[2]
         + bf2f((unsigned short)(p1 >> 16)) * rw[3];
    }
    part[rt] = p;
  }
#pragma unroll
  for (int rt = 0; rt < 4; ++rt) {
    part[rt] += __shfl_xor(part[rt], 16, 64);
    part[rt] += __shfl_xor(part[rt], 32, 64);
  }
  if (q == 0) {
#pragma unroll
    for (int rt = 0; rt < 4; ++rt) Fp[wid][rt * 16 + r15] = part[rt];
  }
  __syncthreads();
  if (tid < 64) {
    float sum = Fp[0][tid] + Fp[1][tid] + Fp[2][tid] + Fp[3][tid];
    const long long r = row0 + tid;
    if (r < nE) Fout[r] = sum;
  }
}

// =====================================================================
// energy MLP: xE[25000][256] -> ssilu(@We_in[256x128]) -> 3 residual(128) -> @We_out
// (small: 196 blocks; unchanged)
// =====================================================================
__global__ __launch_bounds__(256) void energy_kernel(
    const float* __restrict__ xE, const char* __restrict__ EWt0,
    const char* __restrict__ EWtR, const float* __restrict__ We_out,
    float* __restrict__ Eout, int nA) {
  __shared__ char xbuf[32768];  // [128][256B], swz key (row&15)<<4
  __shared__ char wbuf[16384];
  const int tid = threadIdx.x;
  const int lane = tid & 63, q = lane >> 4, r15 = lane & 15;
  const int wid = tid >> 6, wrow = wid * 32;
  const long long row0 = (long long)blockIdx.x * 128;
  const f32x4 zf = {0.f, 0.f, 0.f, 0.f};

  bf16x8 a[2][8];
  unsigned xs[4][2][2][2];

#pragma unroll
  for (int fr = 0; fr < 2; ++fr) {
#pragma unroll
    for (int ks = 0; ks < 8; ++ks) {
      long long rg = row0 + wrow + fr * 16 + r15;
      bf16x8 t = {0, 0, 0, 0, 0, 0, 0, 0};
      if (rg < nA) {
        const float* p = xE + rg * 256 + ks * 32 + q * 8;
        float4 v0 = *(const float4*)p;
        float4 v1 = *(const float4*)(p + 4);
        t[0] = (short)f2bf(v0.x); t[1] = (short)f2bf(v0.y);
        t[2] = (short)f2bf(v0.z); t[3] = (short)f2bf(v0.w);
        t[4] = (short)f2bf(v1.x); t[5] = (short)f2bf(v1.y);
        t[6] = (short)f2bf(v1.z); t[7] = (short)f2bf(v1.w);
      }
      a[fr][ks] = t;
    }
  }

  for (int s = 0; s < 7; ++s) {
    const int K2 = (s == 0) ? 512 : 256;  // bytes per weight row
    const int wchunk = 32 * K2;
    const int nld = wchunk >> 12;         // 4 or 2 16B-loads per thread
    const char* wsrc = (s == 0) ? EWt0 : (EWtR + (unsigned long long)(s - 1) * 32768);
    const int isS0 = (s == 0);
    const int isRes = (s >= 2) && ((s & 1) == 0);
#pragma unroll
    for (int c = 0; c < 4; ++c) {
      for (int i = 0; i < nld; ++i)
        gl16(wsrc + c * wchunk + i * 4096 + tid * 16, wbuf + i * 4096 + tid * 16);
      asm volatile("s_waitcnt vmcnt(0)" ::: "memory");
      __syncthreads();

      f32x4 acc[2][2] = {{zf, zf}, {zf, zf}};
      if (s == 0) {
#pragma unroll
        for (int ks = 0; ks < 8; ++ks) {
          const int kb = ks * 64 + q * 16;
          const int ci0 = r15, ci1 = 16 + r15;
          bf16x8 b0 = *(const bf16x8*)(wbuf + ci0 * 512 + (kb ^ ((ci0 & 15) << 4)));
          bf16x8 b1 = *(const bf16x8*)(wbuf + ci1 * 512 + (kb ^ ((ci1 & 15) << 4)));
          acc[0][0] = __builtin_amdgcn_mfma_f32_16x16x32_bf16(a[0][ks], b0, acc[0][0], 0, 0, 0);
          acc[1][0] = __builtin_amdgcn_mfma_f32_16x16x32_bf16(a[1][ks], b0, acc[1][0], 0, 0, 0);
          acc[0][1] = __builtin_amdgcn_mfma_f32_16x16x32_bf16(a[0][ks], b1, acc[0][1], 0, 0, 0);
          acc[1][1] = __builtin_amdgcn_mfma_f32_16x16x32_bf16(a[1][ks], b1, acc[1][1], 0, 0, 0);
        }
      } else {
#pragma unroll
        for (int ks = 0; ks < 4; ++ks) {
          const int kb = ks * 64 + q * 16;
          const int ci0 = r15, ci1 = 16 + r15;
          bf16x8 b0 = *(const bf16x8*)(wbuf + ci0 * 256 + (kb ^ ((ci0 & 15) << 4)));
          bf16x8 b1 = *(const bf16x8*)(wbuf + ci1 * 256 + (kb ^ ((ci1 & 15) << 4)));
          acc[0][0] = __builtin_amdgcn_mfma_f32_16x16x32_bf16(a[0][ks], b0, acc[0][0], 0, 0, 0);
          acc[1][0] = __builtin_amdgcn_mfma_f32_16x16x32_bf16(a[1][ks], b0, acc[1][0], 0, 0, 0);
          acc[0][1] = __builtin_amdgcn_mfma_f32_16x16x32_bf16(a[0][ks], b1, acc[0][1], 0, 0, 0);
          acc[1][1] = __builtin_amdgcn_mfma_f32_16x16x32_bf16(a[1][ks], b1, acc[1][1], 0, 0, 0);
        }
      }
#pragma unroll
      for (int fr = 0; fr < 2; ++fr) {
#pragma unroll
        for (int fc = 0; fc < 2; ++fc) {
          float o0 = ssilu(acc[fr][fc][0]), o1 = ssilu(acc[fr][fc][1]);
          float o2 = ssilu(acc[fr][fc][2]), o3 = ssilu(acc[fr][fc][3]);
          if (isRes) {
            const unsigned p0 = xs[c][fr][fc][0], p1 = xs[c][fr][fc][1];
            o0 = (bf2f((unsigned short)(p0 & 0xffff)) + o0) * INV_SQRT2;
            o1 = (bf2f((unsigned short)(p0 >> 16)) + o1) * INV_SQRT2;
            o2 = (bf2f((unsigned short)(p1 & 0xffff)) + o2) * INV_SQRT2;
            o3 = (bf2f((unsigned short)(p1 >> 16)) + o3) * INV_SQRT2;
          }
          const unsigned short h0 = f2bf(o0), h1 = f2bf(o1), h2 = f2bf(o2), h3 = f2bf(o3);
          if (isS0 | isRes) {
            xs[c][fr][fc][0] = (unsigned)h0 | ((unsigned)h1 << 16);
            xs[c][fr][fc][1] = (unsigned)h2 | ((unsigned)h3 << 16);
          }
          if (s < 6) {
            const int colb = (c * 32 + fc * 16 + r15) * 2;
            const int rb = wrow + fr * 16 + q * 4;
            *(unsigned short*)(xbuf + (rb + 0) * 256 + (colb ^ (((rb + 0) & 15) << 4))) = h0;
            *(unsigned short*)(xbuf + (rb + 1) * 256 + (colb ^ (((rb + 1) & 15) << 4))) = h1;
            *(unsigned short*)(xbuf + (rb + 2) * 256 + (colb ^ (((rb + 2) & 15) << 4))) = h2;
            *(unsigned short*)(xbuf + (rb + 3) * 256 + (colb ^ (((rb + 3) & 15) << 4))) = h3;
          }
        }
      }
      __syncthreads();
    }
    if (s < 6) {
#pragma unroll
      for (int fr = 0; fr < 2; ++fr) {
#pragma unroll
        for (int ks = 0; ks < 4; ++ks) {
          const int row = wrow + fr * 16 + r15;
          const int kb = ks * 64 + q * 16;
          a[fr][ks] = *(const bf16x8*)(xbuf + row * 256 + (kb ^ (r15 << 4)));
        }
      }
      __syncthreads();
    }
  }

  // final: E[row] = sum_c x[row,c] * We_out[c]
  float psum[2][4] = {{0.f, 0.f, 0.f, 0.f}, {0.f, 0.f, 0.f, 0.f}};
#pragma unroll
  for (int c = 0; c < 4; ++c) {
#pragma unroll
    for (int f = 0; f < 2; ++f) {
      const int col = c * 32 + f * 16 + r15;
      const float wo = We_out[col];
#pragma unroll
      for (int fr = 0; fr < 2; ++fr) {
        const unsigned p0 = xs[c][fr][f][0], p1 = xs[c][fr][f][1];
        psum[fr][0] += bf2f((unsigned short)(p0 & 0xffff)) * wo;
        psum[fr][1] += bf2f((unsigned short)(p0 >> 16)) * wo;
        psum[fr][2] += bf2f((unsigned short)(p1 & 0xffff)) * wo;
        psum[fr][3] += bf2f((unsigned short)(p1 >> 16)) * wo;
      }
    }
  }
#pragma unroll
  for (int off = 1; off < 16; off <<= 1) {
#pragma unroll
    for (int fr = 0; fr < 2; ++fr) {
#pragma unroll
      for (int j = 0; j < 4; ++j) psum[fr][j] += __shfl_xor(psum[fr][j], off, 64);
    }
  }
  if (r15 == 0) {
#pragma unroll
    for (int fr = 0; fr < 2; ++fr) {
#pragma unroll
      for (int j = 0; j < 4; ++j) {
        const long long rg = row0 + wrow + fr * 16 + q * 4 + j;
        if (rg < nA) Eout[rg] = psum[fr][j];
      }
    }
  }
}

// =====================================================================
extern "C" void kernel_launch(void* const* d_in, const int* in_sizes, int n_in,
                              void* d_out, int out_size, void* d_ws, size_t ws_size,
                              hipStream_t stream) {
  const float* m      = (const float*)d_in[1];
  const float* rbf    = (const float*)d_in[2];
  const int*   id_j   = (const int*)d_in[3];
  const float* We_rbf = (const float*)d_in[4];
  const float* We_in  = (const float*)d_in[5];
  const float* We_res = (const float*)d_in[6];
  const float* We_out = (const float*)d_in[7];
  const float* Wf_rbf = (const float*)d_in[8];
  const float* Wf_in  = (const float*)d_in[9];
  const float* Wf_res = (const float*)d_in[10];
  const float* Wf_out = (const float*)d_in[11];
  const int nA = in_sizes[0] / 128;   // 25000
  const int nE = in_sizes[1] / 256;   // 400000

  char* ws = (char*)d_ws;
  float* xE = (float*)(ws + XE_OFF);
  float* Eout = (float*)d_out;
  float* Fout = Eout + nA;

  prep_kernel<<<2368, 256, 0, stream>>>(We_rbf, We_in, We_res, Wf_rbf, Wf_in, Wf_res, Wf_out, ws);
  hipMemsetAsync(xE, 0, (size_t)nA * 256 * 4, stream);
  scatter_kernel<<<(nE + 127) / 128, 256, 0, stream>>>(m, rbf, id_j, ws + W2E_OFF, xE, nE);
  energy_kernel<<<(nA + 127) / 128, 256, 0, stream>>>(xE, ws + EWT0_OFF, ws + EWTR_OFF, We_out, Eout, nA);
  force_kernel<<<(nE + 63) / 64, 256, 0, stream>>>(m, rbf, ws + FWT_OFF, ws + W2F_OFF, Fout, nE);
}

// Round 10
// 840.739 us; speedup vs baseline: 1.6841x; 1.1981x over previous
//
#include <hip/hip_runtime.h>
#include <hip/hip_bf16.h>
#include <stdint.h>

// GemNet OutputBlock fused kernels for MI355X (gfx950).
// E = MLP(segment_sum(m .* (rbf@We_rbf))) @ We_out
// F = (ResMLP(ssilu(m@Wf_in)) .* (rbf@Wf_rbf)) @ Wf_out
//
// R10 = R9 with the compile fix:
//  - pack_bf16 via two scalar __float2bfloat16 casts + shift/or (compiler
//    fuses to v_cvt_pk_bf16_f32; __hip_bfloat162 is not trivially copyable
//    so __builtin_bit_cast on it was rejected).
//  - (void)hipMemsetAsync to silence nodiscard.
// R9 content: hw bf16 converts in force/energy epilogues (attacks 52%
// VALUBusy), scatter -> CSR-gather (count/scan/fill/gather, zero f32 atomics).

typedef __attribute__((ext_vector_type(8))) short bf16x8;
typedef __attribute__((ext_vector_type(4))) float f32x4;
typedef __attribute__((ext_vector_type(2))) unsigned u32x2;
typedef __attribute__((ext_vector_type(4))) unsigned u32x4;

#define INV_SQRT2 0.7071067811865476f

// ---- workspace layout (bytes) ----
#define XE_OFF     0ull
#define XE_BYTES   25600000ull                 // xE f32 [25000][256]
#define FWT_OFF    (XE_OFF + XE_BYTES)
#define FWT_BYTES  917504ull                   // FWR: 7 x [4 w][4 h][8 ks][64 lane]x16B
#define EWT0_OFF   (FWT_OFF + FWT_BYTES)
#define EWT0_BYTES 65536ull                    // [128][256] bf16
#define EWTR_OFF   (EWT0_OFF + EWT0_BYTES)
#define EWTR_BYTES 196608ull                   // 6 x [128][128] bf16
#define W2F_OFF    (EWTR_OFF + EWTR_BYTES)
#define W2F_BYTES  16384ull                    // W2FR: [4 w][4 h][64 lane]x16B
#define W2E_OFF    (W2F_OFF + W2F_BYTES)
#define W2E_BYTES  16384ull                    // (legacy, unused)
#define CNT_OFF    (W2E_OFF + W2E_BYTES)
#define CNT_BYTES  100096ull                   // counts [25000] i32 (padded)
#define OFFS_OFF   (CNT_OFF + CNT_BYTES)
#define OFFS_BYTES 100096ull                   // offsets [25001] i32
#define CURS_OFF   (OFFS_OFF + OFFS_BYTES)
#define CURS_BYTES 100096ull                   // cursors [25000] i32
#define ELIST_OFF  (CURS_OFF + CURS_BYTES)
#define ELIST_BYTES 1600000ull                 // elist [400000] i32

static __device__ __forceinline__ unsigned short f2bf(float f) {
  return __builtin_bit_cast(unsigned short, __float2bfloat16(f));
}
static __device__ __forceinline__ unsigned pack_bf16(float a, float b) {
  // two scalar RNE casts; compiler fuses to v_cvt_pk_bf16_f32 (m240 path)
  const unsigned lo = __builtin_bit_cast(unsigned short, __float2bfloat16(a));
  const unsigned hi = __builtin_bit_cast(unsigned short, __float2bfloat16(b));
  return lo | (hi << 16);
}
static __device__ __forceinline__ float bflo(unsigned p) {
  return __builtin_bit_cast(float, p << 16);
}
static __device__ __forceinline__ float bfhi(unsigned p) {
  return __builtin_bit_cast(float, p & 0xffff0000u);
}
static __device__ __forceinline__ float ssilu(float x) {
  // silu(x)/0.6 = x * sigmoid(x) * 5/3
  return 1.6666666666666667f * x * __builtin_amdgcn_rcpf(1.0f + __expf(-x));
}
static __device__ __forceinline__ void gl16(const void* g, void* l) {
  __builtin_amdgcn_global_load_lds(
      (const __attribute__((address_space(1))) void*)(unsigned long long)(uintptr_t)g,
      (__attribute__((address_space(3))) void*)(unsigned)(uintptr_t)l, 16, 0, 0);
}

// =====================================================================
// prep: weights f32 -> bf16 into frag-ready layouts (unchanged from R8).
// =====================================================================
__global__ void prep_kernel(const float* __restrict__ We_rbf,
                            const float* __restrict__ We_in,
                            const float* __restrict__ We_res,
                            const float* __restrict__ Wf_rbf,
                            const float* __restrict__ Wf_in,
                            const float* __restrict__ Wf_res,
                            const float* __restrict__ Wf_out,
                            char* __restrict__ ws) {
  int idx = blockIdx.x * 256 + threadIdx.x;
  if (idx < 458752) {  // FWR
    int s = idx >> 16, r = idx & 65535;
    int w = r >> 14, h = (r >> 12) & 3, ks = (r >> 9) & 7, lane = (r >> 3) & 63, e = r & 7;
    int c = w * 64 + h * 16 + (lane & 15);
    int k = ks * 32 + (lane >> 4) * 8 + e;
    float v = (s == 0) ? Wf_in[k * 256 + c] : Wf_res[(s - 1) * 65536 + k * 256 + c];
    *(unsigned short*)(ws + FWT_OFF + (unsigned long long)s * 131072 + (unsigned)r * 2) = f2bf(v);
    return;
  }
  idx -= 458752;
  if (idx < 32768) {  // EWt0: [k=256][c=128] -> [c][k]
    int k = idx >> 7, c = idx & 127;
    *(unsigned short*)(ws + EWT0_OFF + c * 512 + ((k * 2) ^ ((c & 15) << 4))) = f2bf(We_in[k * 128 + c]);
    return;
  }
  idx -= 32768;
  if (idx < 98304) {  // EWtR: 6 stages [k=128][c=128] -> [c][k], rows 256B
    int s = idx >> 14, r = idx & 16383, k = r >> 7, c = r & 127;
    *(unsigned short*)(ws + EWTR_OFF + (unsigned long long)s * 32768 +
                       c * 256 + ((k * 2) ^ ((c & 15) << 4))) = f2bf(We_res[s * 16384 + k * 128 + c]);
    return;
  }
  idx -= 98304;
  if (idx < 8192) {  // W2FR
    int w = idx >> 11, h = (idx >> 9) & 3, lane = (idx >> 3) & 63, e = idx & 7;
    int c = w * 64 + h * 16 + (lane & 15);
    int k = (lane >> 4) * 8 + e;
    float v = (k < 16) ? Wf_rbf[k * 256 + c] * Wf_out[c] : 0.f;
    *(unsigned short*)(ws + W2F_OFF + (unsigned)idx * 2) = f2bf(v);
    return;
  }
}

// =====================================================================
// CSR build: count -> scan -> fill
// =====================================================================
__global__ __launch_bounds__(256) void count_kernel(
    const int* __restrict__ id_j, int* __restrict__ cnt, int nE) {
  int e = blockIdx.x * 256 + threadIdx.x;
  if (e < nE) atomicAdd(&cnt[id_j[e]], 1);
}

__global__ __launch_bounds__(1024) void scan_kernel(
    const int* __restrict__ cnt, int* __restrict__ offs,
    int* __restrict__ curs, int nA) {
  __shared__ int ps[1024];
  const int t = threadIdx.x;
  const int per = (nA + 1023) / 1024;
  const int lo = t * per, hi = min(lo + per, nA);
  int s = 0;
  for (int i = lo; i < hi; ++i) s += cnt[i];
  ps[t] = s;
  __syncthreads();
  for (int off = 1; off < 1024; off <<= 1) {
    int v = 0;
    if (t >= off) v = ps[t - off];
    __syncthreads();
    ps[t] += v;
    __syncthreads();
  }
  int run = (t == 0) ? 0 : ps[t - 1];
  for (int i = lo; i < hi; ++i) {
    offs[i] = run; curs[i] = run; run += cnt[i];
  }
  if (t == 0) offs[nA] = ps[1023];
}

__global__ __launch_bounds__(256) void fill_kernel(
    const int* __restrict__ id_j, int* __restrict__ curs,
    int* __restrict__ elist, int nE) {
  int e = blockIdx.x * 256 + threadIdx.x;
  if (e < nE) {
    int p = atomicAdd(&curs[id_j[e]], 1);
    elist[p] = e;
  }
}

// =====================================================================
// gather: xE[a][c] = sum_{e in edges(a)} m[e][c] * (rbf[e] @ We_rbf)[c]
// block = atom (25000), thread = col (256). No atomics, f32 throughout.
// rbf[e] loads are wave-uniform (scalar path); m loads coalesced.
// =====================================================================
__global__ __launch_bounds__(256) void gather_kernel(
    const float* __restrict__ m, const float* __restrict__ rbf,
    const int* __restrict__ elist, const int* __restrict__ offs,
    const float* __restrict__ We_rbf, float* __restrict__ xE) {
  __shared__ float Wl[16][256];
  const int a = blockIdx.x;
  const int c = threadIdx.x;
#pragma unroll
  for (int k = 0; k < 16; ++k) Wl[k][c] = We_rbf[k * 256 + c];
  __syncthreads();
  const int beg = offs[a], end = offs[a + 1];
  float acc = 0.f;
  for (int j = beg; j < end; ++j) {
    const int e = elist[j];
    const float* rp = rbf + (long long)e * 16;
    float rw = 0.f;
#pragma unroll
    for (int k = 0; k < 16; ++k) rw = fmaf(rp[k], Wl[k][c], rw);
    acc = fmaf(m[(long long)e * 256 + c], rw, acc);
  }
  xE[(long long)a * 256 + c] = acc;
}

// =====================================================================
// force (column-sliced, R8 structure + hw bf16 conversions):
// 6250 blocks x 256 thr (4 waves); block = 64 rows; wave owns 64 cols.
// =====================================================================
__global__ __launch_bounds__(256, 2) void force_kernel(
    const float* __restrict__ m, const float* __restrict__ rbf,
    const char* __restrict__ FWR, const char* __restrict__ W2FR,
    float* __restrict__ Fout, int nE) {
  __shared__ char Xbuf[2][32768];  // [64 rows][512B], swz key (row&15)<<4
  __shared__ float Fp[4][64];      // per-wave partial F
  const int tid = threadIdx.x;
  const int lane = tid & 63, q = lane >> 4, r15 = lane & 15;
  const int wid = tid >> 6;        // 0..3: cols 64*wid..+63
  const long long row0 = (long long)blockIdx.x * 64;
  const f32x4 zf = {0.f, 0.f, 0.f, 0.f};

  // ---- prologue: m -> X[0] (bf16, swizzled) ----
  {
    const int row = tid >> 2, c0 = (tid & 3) * 64;
    long long rg = row0 + row; if (rg >= nE) rg = nE - 1;
    const float* mp = m + rg * 256 + c0;
    const int key = (row & 15) << 4;
#pragma unroll
    for (int i = 0; i < 8; ++i) {
      float4 v0 = *(const float4*)(mp + i * 8);
      float4 v1 = *(const float4*)(mp + i * 8 + 4);
      u32x4 p;
      p[0] = pack_bf16(v0.x, v0.y);
      p[1] = pack_bf16(v0.z, v0.w);
      p[2] = pack_bf16(v1.x, v1.y);
      p[3] = pack_bf16(v1.z, v1.w);
      *(u32x4*)(Xbuf[0] + row * 512 + (((c0 + i * 8) * 2) ^ key)) = p;
    }
  }
  __syncthreads();

  bf16x8 W[4][8];          // wave's 64-col W-slice
  unsigned xs[4][4][2];    // residual checkpoint: [rt][h][pair of 2 bf16]

  for (int s = 0; s < 7; ++s) {
    const char* wbase = FWR + (unsigned long long)s * 131072 + wid * 32768;
#pragma unroll
    for (int h = 0; h < 4; ++h)
#pragma unroll
      for (int ks = 0; ks < 8; ++ks)
        W[h][ks] = *(const bf16x8*)(wbase + h * 8192 + ks * 1024 + lane * 16);

    const int cur = s & 1;
    const char* Xr = (const char*)Xbuf + cur * 32768;
    char* Xw = (char*)Xbuf + (cur ^ 1) * 32768;
    const bool isS0 = (s == 0);
    const bool isRes = (s >= 2) && !(s & 1);

#pragma unroll
    for (int rt = 0; rt < 4; ++rt) {
      const int row = rt * 16 + r15;
      const int key = (row & 15) << 4;
      f32x4 a[4] = {zf, zf, zf, zf};
#pragma unroll
      for (int ks = 0; ks < 8; ++ks) {
        bf16x8 b = *(const bf16x8*)(Xr + row * 512 + ((ks * 64 + q * 16) ^ key));
        a[0] = __builtin_amdgcn_mfma_f32_16x16x32_bf16(W[0][ks], b, a[0], 0, 0, 0);
        a[1] = __builtin_amdgcn_mfma_f32_16x16x32_bf16(W[1][ks], b, a[1], 0, 0, 0);
        a[2] = __builtin_amdgcn_mfma_f32_16x16x32_bf16(W[2][ks], b, a[2], 0, 0, 0);
        a[3] = __builtin_amdgcn_mfma_f32_16x16x32_bf16(W[3][ks], b, a[3], 0, 0, 0);
      }
#pragma unroll
      for (int h = 0; h < 4; ++h) {
        float o0 = ssilu(a[h][0]), o1 = ssilu(a[h][1]);
        float o2 = ssilu(a[h][2]), o3 = ssilu(a[h][3]);
        if (isRes) {
          const unsigned p0 = xs[rt][h][0], p1 = xs[rt][h][1];
          o0 = (bflo(p0) + o0) * INV_SQRT2;
          o1 = (bfhi(p0) + o1) * INV_SQRT2;
          o2 = (bflo(p1) + o2) * INV_SQRT2;
          o3 = (bfhi(p1) + o3) * INV_SQRT2;
        }
        const unsigned h01 = pack_bf16(o0, o1);
        const unsigned h23 = pack_bf16(o2, o3);
        if (isS0 | isRes) { xs[rt][h][0] = h01; xs[rt][h][1] = h23; }
        if (s < 6) {
          u32x2 p; p[0] = h01; p[1] = h23;
          *(u32x2*)(Xw + row * 512 + (((wid * 64 + h * 16 + q * 4) * 2) ^ key)) = p;
        }
      }
    }
    __syncthreads();
  }

  // ---- final: rw = rbf @ (Wf_rbf .* Wf_out) slice; F partial = x6 . rw ----
  bf16x8 A2[4];
#pragma unroll
  for (int h = 0; h < 4; ++h)
    A2[h] = *(const bf16x8*)(W2FR + wid * 4096 + h * 1024 + lane * 16);

  float part[4];
#pragma unroll
  for (int rt = 0; rt < 4; ++rt) {
    const int row = rt * 16 + r15;
    long long rg = row0 + row; if (rg >= nE) rg = nE - 1;
    bf16x8 br = {0, 0, 0, 0, 0, 0, 0, 0};
    if (q < 2) {  // B-frag k = q*8+e (<16); k>=16 padded zero
      const float* p = rbf + rg * 16 + q * 8;
      float4 v0 = *(const float4*)p;
      float4 v1 = *(const float4*)(p + 4);
      br[0] = (short)f2bf(v0.x); br[1] = (short)f2bf(v0.y);
      br[2] = (short)f2bf(v0.z); br[3] = (short)f2bf(v0.w);
      br[4] = (short)f2bf(v1.x); br[5] = (short)f2bf(v1.y);
      br[6] = (short)f2bf(v1.z); br[7] = (short)f2bf(v1.w);
    }
    float p = 0.f;
#pragma unroll
    for (int h = 0; h < 4; ++h) {
      f32x4 rw = __builtin_amdgcn_mfma_f32_16x16x32_bf16(A2[h], br, zf, 0, 0, 0);
      const unsigned p0 = xs[rt][h][0], p1 = xs[rt][h][1];
      p += bflo(p0) * rw[0] + bfhi(p0) * rw[1] + bflo(p1) * rw[2] + bfhi(p1) * rw[3];
    }
    part[rt] = p;
  }
#pragma unroll
  for (int rt = 0; rt < 4; ++rt) {
    part[rt] += __shfl_xor(part[rt], 16, 64);
    part[rt] += __shfl_xor(part[rt], 32, 64);
  }
  if (q == 0) {
#pragma unroll
    for (int rt = 0; rt < 4; ++rt) Fp[wid][rt * 16 + r15] = part[rt];
  }
  __syncthreads();
  if (tid < 64) {
    float sum = Fp[0][tid] + Fp[1][tid] + Fp[2][tid] + Fp[3][tid];
    const long long r = row0 + tid;
    if (r < nE) Fout[r] = sum;
  }
}

// =====================================================================
// energy MLP: xE[25000][256] -> ssilu(@We_in[256x128]) -> 3 residual(128) -> @We_out
// (hw bf16 conversions; structure unchanged)
// =====================================================================
__global__ __launch_bounds__(256) void energy_kernel(
    const float* __restrict__ xE, const char* __restrict__ EWt0,
    const char* __restrict__ EWtR, const float* __restrict__ We_out,
    float* __restrict__ Eout, int nA) {
  __shared__ char xbuf[32768];  // [128][256B], swz key (row&15)<<4
  __shared__ char wbuf[16384];
  const int tid = threadIdx.x;
  const int lane = tid & 63, q = lane >> 4, r15 = lane & 15;
  const int wid = tid >> 6, wrow = wid * 32;
  const long long row0 = (long long)blockIdx.x * 128;
  const f32x4 zf = {0.f, 0.f, 0.f, 0.f};

  bf16x8 a[2][8];
  unsigned xs[4][2][2][2];

#pragma unroll
  for (int fr = 0; fr < 2; ++fr) {
#pragma unroll
    for (int ks = 0; ks < 8; ++ks) {
      long long rg = row0 + wrow + fr * 16 + r15;
      bf16x8 t = {0, 0, 0, 0, 0, 0, 0, 0};
      if (rg < nA) {
        const float* p = xE + rg * 256 + ks * 32 + q * 8;
        float4 v0 = *(const float4*)p;
        float4 v1 = *(const float4*)(p + 4);
        t[0] = (short)f2bf(v0.x); t[1] = (short)f2bf(v0.y);
        t[2] = (short)f2bf(v0.z); t[3] = (short)f2bf(v0.w);
        t[4] = (short)f2bf(v1.x); t[5] = (short)f2bf(v1.y);
        t[6] = (short)f2bf(v1.z); t[7] = (short)f2bf(v1.w);
      }
      a[fr][ks] = t;
    }
  }

  for (int s = 0; s < 7; ++s) {
    const int K2 = (s == 0) ? 512 : 256;  // bytes per weight row
    const int wchunk = 32 * K2;
    const int nld = wchunk >> 12;         // 4 or 2 16B-loads per thread
    const char* wsrc = (s == 0) ? EWt0 : (EWtR + (unsigned long long)(s - 1) * 32768);
    const int isS0 = (s == 0);
    const int isRes = (s >= 2) && ((s & 1) == 0);
#pragma unroll
    for (int c = 0; c < 4; ++c) {
      for (int i = 0; i < nld; ++i)
        gl16(wsrc + c * wchunk + i * 4096 + tid * 16, wbuf + i * 4096 + tid * 16);
      asm volatile("s_waitcnt vmcnt(0)" ::: "memory");
      __syncthreads();

      f32x4 acc[2][2] = {{zf, zf}, {zf, zf}};
      if (s == 0) {
#pragma unroll
        for (int ks = 0; ks < 8; ++ks) {
          const int kb = ks * 64 + q * 16;
          const int ci0 = r15, ci1 = 16 + r15;
          bf16x8 b0 = *(const bf16x8*)(wbuf + ci0 * 512 + (kb ^ ((ci0 & 15) << 4)));
          bf16x8 b1 = *(const bf16x8*)(wbuf + ci1 * 512 + (kb ^ ((ci1 & 15) << 4)));
          acc[0][0] = __builtin_amdgcn_mfma_f32_16x16x32_bf16(a[0][ks], b0, acc[0][0], 0, 0, 0);
          acc[1][0] = __builtin_amdgcn_mfma_f32_16x16x32_bf16(a[1][ks], b0, acc[1][0], 0, 0, 0);
          acc[0][1] = __builtin_amdgcn_mfma_f32_16x16x32_bf16(a[0][ks], b1, acc[0][1], 0, 0, 0);
          acc[1][1] = __builtin_amdgcn_mfma_f32_16x16x32_bf16(a[1][ks], b1, acc[1][1], 0, 0, 0);
        }
      } else {
#pragma unroll
        for (int ks = 0; ks < 4; ++ks) {
          const int kb = ks * 64 + q * 16;
          const int ci0 = r15, ci1 = 16 + r15;
          bf16x8 b0 = *(const bf16x8*)(wbuf + ci0 * 256 + (kb ^ ((ci0 & 15) << 4)));
          bf16x8 b1 = *(const bf16x8*)(wbuf + ci1 * 256 + (kb ^ ((ci1 & 15) << 4)));
          acc[0][0] = __builtin_amdgcn_mfma_f32_16x16x32_bf16(a[0][ks], b0, acc[0][0], 0, 0, 0);
          acc[1][0] = __builtin_amdgcn_mfma_f32_16x16x32_bf16(a[1][ks], b0, acc[1][0], 0, 0, 0);
          acc[0][1] = __builtin_amdgcn_mfma_f32_16x16x32_bf16(a[0][ks], b1, acc[0][1], 0, 0, 0);
          acc[1][1] = __builtin_amdgcn_mfma_f32_16x16x32_bf16(a[1][ks], b1, acc[1][1], 0, 0, 0);
        }
      }
#pragma unroll
      for (int fr = 0; fr < 2; ++fr) {
#pragma unroll
        for (int fc = 0; fc < 2; ++fc) {
          float o0 = ssilu(acc[fr][fc][0]), o1 = ssilu(acc[fr][fc][1]);
          float o2 = ssilu(acc[fr][fc][2]), o3 = ssilu(acc[fr][fc][3]);
          if (isRes) {
            const unsigned p0 = xs[c][fr][fc][0], p1 = xs[c][fr][fc][1];
            o0 = (bflo(p0) + o0) * INV_SQRT2;
            o1 = (bfhi(p0) + o1) * INV_SQRT2;
            o2 = (bflo(p1) + o2) * INV_SQRT2;
            o3 = (bfhi(p1) + o3) * INV_SQRT2;
          }
          const unsigned h01 = pack_bf16(o0, o1);
          const unsigned h23 = pack_bf16(o2, o3);
          if (isS0 | isRes) {
            xs[c][fr][fc][0] = h01;
            xs[c][fr][fc][1] = h23;
          }
          if (s < 6) {
            const int colb = (c * 32 + fc * 16 + r15) * 2;
            const int rb = wrow + fr * 16 + q * 4;
            *(unsigned short*)(xbuf + (rb + 0) * 256 + (colb ^ (((rb + 0) & 15) << 4))) = (unsigned short)(h01 & 0xffff);
            *(unsigned short*)(xbuf + (rb + 1) * 256 + (colb ^ (((rb + 1) & 15) << 4))) = (unsigned short)(h01 >> 16);
            *(unsigned short*)(xbuf + (rb + 2) * 256 + (colb ^ (((rb + 2) & 15) << 4))) = (unsigned short)(h23 & 0xffff);
            *(unsigned short*)(xbuf + (rb + 3) * 256 + (colb ^ (((rb + 3) & 15) << 4))) = (unsigned short)(h23 >> 16);
          }
        }
      }
      __syncthreads();
    }
    if (s < 6) {
#pragma unroll
      for (int fr = 0; fr < 2; ++fr) {
#pragma unroll
        for (int ks = 0; ks < 4; ++ks) {
          const int row = wrow + fr * 16 + r15;
          const int kb = ks * 64 + q * 16;
          a[fr][ks] = *(const bf16x8*)(xbuf + row * 256 + (kb ^ (r15 << 4)));
        }
      }
      __syncthreads();
    }
  }

  // final: E[row] = sum_c x[row,c] * We_out[c]
  float psum[2][4] = {{0.f, 0.f, 0.f, 0.f}, {0.f, 0.f, 0.f, 0.f}};
#pragma unroll
  for (int c = 0; c < 4; ++c) {
#pragma unroll
    for (int f = 0; f < 2; ++f) {
      const int col = c * 32 + f * 16 + r15;
      const float wo = We_out[col];
#pragma unroll
      for (int fr = 0; fr < 2; ++fr) {
        const unsigned p0 = xs[c][fr][f][0], p1 = xs[c][fr][f][1];
        psum[fr][0] += bflo(p0) * wo;
        psum[fr][1] += bfhi(p0) * wo;
        psum[fr][2] += bflo(p1) * wo;
        psum[fr][3] += bfhi(p1) * wo;
      }
    }
  }
#pragma unroll
  for (int off = 1; off < 16; off <<= 1) {
#pragma unroll
    for (int fr = 0; fr < 2; ++fr) {
#pragma unroll
      for (int j = 0; j < 4; ++j) psum[fr][j] += __shfl_xor(psum[fr][j], off, 64);
    }
  }
  if (r15 == 0) {
#pragma unroll
    for (int fr = 0; fr < 2; ++fr) {
#pragma unroll
      for (int j = 0; j < 4; ++j) {
        const long long rg = row0 + wrow + fr * 16 + q * 4 + j;
        if (rg < nA) Eout[rg] = psum[fr][j];
      }
    }
  }
}

// =====================================================================
extern "C" void kernel_launch(void* const* d_in, const int* in_sizes, int n_in,
                              void* d_out, int out_size, void* d_ws, size_t ws_size,
                              hipStream_t stream) {
  const float* m      = (const float*)d_in[1];
  const float* rbf    = (const float*)d_in[2];
  const int*   id_j   = (const int*)d_in[3];
  const float* We_rbf = (const float*)d_in[4];
  const float* We_in  = (const float*)d_in[5];
  const float* We_res = (const float*)d_in[6];
  const float* We_out = (const float*)d_in[7];
  const float* Wf_rbf = (const float*)d_in[8];
  const float* Wf_in  = (const float*)d_in[9];
  const float* Wf_res = (const float*)d_in[10];
  const float* Wf_out = (const float*)d_in[11];
  const int nA = in_sizes[0] / 128;   // 25000
  const int nE = in_sizes[1] / 256;   // 400000

  char* ws = (char*)d_ws;
  float* xE   = (float*)(ws + XE_OFF);
  int*   cnt  = (int*)(ws + CNT_OFF);
  int*   offs = (int*)(ws + OFFS_OFF);
  int*   curs = (int*)(ws + CURS_OFF);
  int*   elist= (int*)(ws + ELIST_OFF);
  float* Eout = (float*)d_out;
  float* Fout = Eout + nA;

  prep_kernel<<<2368, 256, 0, stream>>>(We_rbf, We_in, We_res, Wf_rbf, Wf_in, Wf_res, Wf_out, ws);
  (void)hipMemsetAsync(cnt, 0, (size_t)nA * 4, stream);
  count_kernel<<<(nE + 255) / 256, 256, 0, stream>>>(id_j, cnt, nE);
  scan_kernel<<<1, 1024, 0, stream>>>(cnt, offs, curs, nA);
  fill_kernel<<<(nE + 255) / 256, 256, 0, stream>>>(id_j, curs, elist, nE);
  gather_kernel<<<nA, 256, 0, stream>>>(m, rbf, elist, offs, We_rbf, xE);
  energy_kernel<<<(nA + 127) / 128, 256, 0, stream>>>(xE, ws + EWT0_OFF, ws + EWTR_OFF, We_out, Eout, nA);
  force_kernel<<<(nE + 63) / 64, 256, 0, stream>>>(m, rbf, ws + FWT_OFF, ws + W2F_OFF, Fout, nE);
}